// Round 1
// baseline (1115.838 us; speedup 1.0000x reference)
//
#include <hip/hip_runtime.h>
#include <hip/hip_bf16.h>

namespace {

constexpr int N    = 65536;
constexpr int E    = 1048576;
constexpr int B    = 128;
constexpr int NPG  = 512;
constexpr int IN   = 128;
constexpr int H    = 64;
constexpr int BINS = 16;
constexpr int FIN  = 2 * H + BINS + 3;  // 147

// ---------------- CSR build (by dst) ----------------

__global__ __launch_bounds__(256) void k_count(const int* __restrict__ dst, int* __restrict__ cnt) {
  for (int e = blockIdx.x * 256 + threadIdx.x; e < E; e += gridDim.x * 256)
    atomicAdd(&cnt[dst[e]], 1);
}

__global__ __launch_bounds__(256) void k_reduce256(const int* __restrict__ cnt, int* __restrict__ bsum) {
  __shared__ int s[256];
  int t = threadIdx.x;
  s[t] = cnt[blockIdx.x * 256 + t];
  __syncthreads();
  for (int d = 128; d > 0; d >>= 1) {
    if (t < d) s[t] += s[t + d];
    __syncthreads();
  }
  if (t == 0) bsum[blockIdx.x] = s[0];
}

__global__ __launch_bounds__(256) void k_scan256(const int* __restrict__ bsum, int* __restrict__ boff) {
  __shared__ int s[256];
  int t = threadIdx.x;
  int v = bsum[t];
  s[t] = v;
  __syncthreads();
  for (int d = 1; d < 256; d <<= 1) {
    int add = (t >= d) ? s[t - d] : 0;
    __syncthreads();
    s[t] += add;
    __syncthreads();
  }
  boff[t] = s[t] - v;  // exclusive
}

__global__ __launch_bounds__(256) void k_scanfin(const int* __restrict__ cnt, const int* __restrict__ boff,
                                                 int* __restrict__ rowptr) {
  __shared__ int s[256];
  int b = blockIdx.x, t = threadIdx.x;
  int idx = b * 256 + t;
  int v = cnt[idx];
  s[t] = v;
  __syncthreads();
  for (int d = 1; d < 256; d <<= 1) {
    int add = (t >= d) ? s[t - d] : 0;
    __syncthreads();
    s[t] += add;
    __syncthreads();
  }
  rowptr[idx] = boff[b] + s[t] - v;
  if (idx == N - 1) rowptr[N] = boff[b] + s[t];
}

__global__ __launch_bounds__(256) void k_fill(const int* __restrict__ src, const int* __restrict__ dst,
                                              const int* __restrict__ rowptr, int* __restrict__ cur,
                                              int* __restrict__ col) {
  for (int e = blockIdx.x * 256 + threadIdx.x; e < E; e += gridDim.x * 256) {
    int d = dst[e];
    int pos = rowptr[d] + atomicAdd(&cur[d], 1);
    col[pos] = src[e];
  }
}

// ---------------- dense helpers ----------------

__device__ __forceinline__ void fma8(float (&acc)[8], const float* p, float wv) {
  float4 lo = *(const float4*)(p);
  float4 hi = *(const float4*)(p + 4);
  acc[0] = fmaf(lo.x, wv, acc[0]);
  acc[1] = fmaf(lo.y, wv, acc[1]);
  acc[2] = fmaf(lo.z, wv, acc[2]);
  acc[3] = fmaf(lo.w, wv, acc[3]);
  acc[4] = fmaf(hi.x, wv, acc[4]);
  acc[5] = fmaf(hi.y, wv, acc[5]);
  acc[6] = fmaf(hi.z, wv, acc[6]);
  acc[7] = fmaf(hi.w, wv, acc[7]);
}

// y = x @ W ; x:[N,IN] W:[IN,H] y:[N,H].  8 nodes per wave.
__global__ __launch_bounds__(256) void k_xw(const float* __restrict__ x, const float* __restrict__ W,
                                            float* __restrict__ y) {
  __shared__ float sW[IN * H];                     // 32 KB
  __shared__ __align__(16) float sx[4][IN][8];     // 16 KB
  int tid = threadIdx.x, lane = tid & 63, sub = tid >> 6;
  for (int i = tid; i < IN * H; i += 256) sW[i] = W[i];
  __syncthreads();
  for (int gi = blockIdx.x; gi < N / 32; gi += gridDim.x) {
    int nbase = gi * 32 + sub * 8;
#pragma unroll
    for (int nd = 0; nd < 8; ++nd) {
      const float* xr = x + (size_t)(nbase + nd) * IN;
      sx[sub][lane][nd]      = xr[lane];
      sx[sub][lane + 64][nd] = xr[lane + 64];
    }
    __syncthreads();
    float acc[8];
#pragma unroll
    for (int nd = 0; nd < 8; ++nd) acc[nd] = 0.f;
    for (int k = 0; k < IN; ++k) {
      float wv = sW[k * H + lane];
      fma8(acc, &sx[sub][k][0], wv);
    }
#pragma unroll
    for (int nd = 0; nd < 8; ++nd) y[(size_t)(nbase + nd) * H + lane] = acc[nd];
    __syncthreads();
  }
}

// Fused: t = relu(in[n] + segsum_{in-edges}(in[src]) + b0); u = relu(t@Wa + ba);
// HASB: out = u @ Wb (no bias/relu).  else: out = u.
template <bool HASB>
__global__ __launch_bounds__(256) void k_fused(const float* __restrict__ in, const int* __restrict__ rowptr,
                                               const int* __restrict__ col, const float* __restrict__ b0v,
                                               const float* __restrict__ Wa, const float* __restrict__ ba,
                                               const float* __restrict__ Wb, float* __restrict__ out) {
  __shared__ float sWa[H * H];                     // 16 KB
  __shared__ float sWb[HASB ? H * H : 1];
  __shared__ __align__(16) float st[4][H][8];      // 8 KB
  int tid = threadIdx.x, lane = tid & 63, sub = tid >> 6;
  for (int i = tid; i < H * H; i += 256) sWa[i] = Wa[i];
  if (HASB)
    for (int i = tid; i < H * H; i += 256) sWb[i] = Wb[i];
  float bias0 = b0v[lane], biasA = ba[lane];
  __syncthreads();
  for (int gi = blockIdx.x; gi < N / 32; gi += gridDim.x) {
    int nbase = gi * 32 + sub * 8;
#pragma unroll
    for (int nd = 0; nd < 8; ++nd) {
      int n = nbase + nd;
      int p0 = rowptr[n], p1 = rowptr[n + 1];
      float a = 0.f;
      for (int p = p0; p < p1; ++p) a += in[(size_t)col[p] * H + lane];
      float t = in[(size_t)n * H + lane] + a + bias0;
      st[sub][lane][nd] = fmaxf(t, 0.f);
    }
    __syncthreads();
    float acc[8];
#pragma unroll
    for (int nd = 0; nd < 8; ++nd) acc[nd] = biasA;
    for (int k = 0; k < H; ++k) {
      float wv = sWa[k * H + lane];
      fma8(acc, &st[sub][k][0], wv);
    }
    if (HASB) {
      __syncthreads();
#pragma unroll
      for (int nd = 0; nd < 8; ++nd) st[sub][lane][nd] = fmaxf(acc[nd], 0.f);
      __syncthreads();
      float acc2[8];
#pragma unroll
      for (int nd = 0; nd < 8; ++nd) acc2[nd] = 0.f;
      for (int k = 0; k < H; ++k) {
        float wv = sWb[k * H + lane];
        fma8(acc2, &st[sub][k][0], wv);
      }
#pragma unroll
      for (int nd = 0; nd < 8; ++nd) out[(size_t)(nbase + nd) * H + lane] = acc2[nd];
    } else {
#pragma unroll
      for (int nd = 0; nd < 8; ++nd) out[(size_t)(nbase + nd) * H + lane] = fmaxf(acc[nd], 0.f);
    }
    __syncthreads();
  }
}

// Per 64-node chunk: L2-normalize rows in place, write partial pool sums pg[bid][64].
__global__ __launch_bounds__(256) void k_poolnorm(float* __restrict__ Hm, float* __restrict__ pg) {
  __shared__ float sacc[4][64];
  int bid = blockIdx.x;
  int gr = bid >> 3, chk = bid & 7;
  int tid = threadIdx.x, lane = tid & 63, sub = tid >> 6;
  float acc = 0.f;
  int n0 = gr * NPG + chk * 64;
  for (int i = sub; i < 64; i += 4) {
    size_t off = (size_t)(n0 + i) * H + lane;
    float v = Hm[off];
    float ss = v * v;
#pragma unroll
    for (int d = 1; d < 64; d <<= 1) ss += __shfl_xor(ss, d, 64);
    Hm[off] = v / fmaxf(sqrtf(ss), 1e-12f);
    acc += v;
  }
  sacc[sub][lane] = acc;
  __syncthreads();
  if (sub == 0) pg[bid * 64 + lane] = sacc[0][lane] + sacc[1][lane] + sacc[2][lane] + sacc[3][lane];
}

// Fused sim + hist + stats. Block = (graph, 64-row tile of side1). Deterministic per-block partials.
__global__ __launch_bounds__(256) void k_sim(const float* __restrict__ H1n, const float* __restrict__ H2n,
                                             float* __restrict__ psum, float* __restrict__ psumsq,
                                             float* __restrict__ pmax, int* __restrict__ phist) {
  __shared__ float s1[64][65];    // +1 pad -> conflict-free reads
  __shared__ float s2[128][65];
  __shared__ int shist[64 * 17];  // 64 replicas, stride 17 (conflict-free lane->replica)
  __shared__ float sred[256];
  int tid = threadIdx.x;
  int g = blockIdx.x >> 3, rt = blockIdx.x & 7;
  for (int i = tid; i < 64 * 17; i += 256) shist[i] = 0;
  const float* base1 = H1n + ((size_t)g * NPG + rt * 64) * H;
  for (int i = tid; i < 64 * 64; i += 256) s1[i >> 6][i & 63] = base1[i];
  int ty = tid >> 4, tx = tid & 15;
  int rep = (tid & 63) * 17;
  float lmax = -2.f, lsum = 0.f, lsumsq = 0.f;
  for (int ch = 0; ch < 4; ++ch) {
    __syncthreads();
    const float* base2 = H2n + ((size_t)g * NPG + ch * 128) * H;
    for (int i = tid; i < 128 * 64; i += 256) s2[i >> 6][i & 63] = base2[i];
    __syncthreads();
    float acc[4][8];
#pragma unroll
    for (int i = 0; i < 4; ++i)
#pragma unroll
      for (int j = 0; j < 8; ++j) acc[i][j] = 0.f;
    for (int k = 0; k < 64; ++k) {
      float a[4], b[8];
#pragma unroll
      for (int i = 0; i < 4; ++i) a[i] = s1[ty + 16 * i][k];
#pragma unroll
      for (int j = 0; j < 8; ++j) b[j] = s2[tx + 16 * j][k];
#pragma unroll
      for (int i = 0; i < 4; ++i)
#pragma unroll
        for (int j = 0; j < 8; ++j) acc[i][j] = fmaf(a[i], b[j], acc[i][j]);
    }
#pragma unroll
    for (int i = 0; i < 4; ++i)
#pragma unroll
      for (int j = 0; j < 8; ++j) {
        float v = acc[i][j];
        lmax = fmaxf(lmax, v);
        lsum += v;
        lsumsq = fmaf(v, v, lsumsq);
        int bin = (int)floorf((v + 1.f) * 8.f);
        bin = bin < 0 ? 0 : (bin > BINS - 1 ? BINS - 1 : bin);
        atomicAdd(&shist[rep + bin], 1);
      }
  }
  sred[tid] = lsum;
  __syncthreads();
  for (int w = 128; w > 0; w >>= 1) {
    if (tid < w) sred[tid] += sred[tid + w];
    __syncthreads();
  }
  if (tid == 0) psum[blockIdx.x] = sred[0];
  __syncthreads();
  sred[tid] = lsumsq;
  __syncthreads();
  for (int w = 128; w > 0; w >>= 1) {
    if (tid < w) sred[tid] += sred[tid + w];
    __syncthreads();
  }
  if (tid == 0) psumsq[blockIdx.x] = sred[0];
  __syncthreads();
  sred[tid] = lmax;
  __syncthreads();
  for (int w = 128; w > 0; w >>= 1) {
    if (tid < w) sred[tid] = fmaxf(sred[tid], sred[tid + w]);
    __syncthreads();
  }
  if (tid == 0) pmax[blockIdx.x] = sred[0];
  __syncthreads();
  if (tid < BINS) {
    int tot = 0;
    for (int r = 0; r < 64; ++r) tot += shist[r * 17 + tid];
    phist[blockIdx.x * BINS + tid] = tot;
  }
}

// Final feature assembly + MLP 147->64->32->1. One block (64 threads) per graph.
__global__ __launch_bounds__(64) void k_final(const float* __restrict__ pg1, const float* __restrict__ pg2,
                                              const float* __restrict__ psum, const float* __restrict__ psumsq,
                                              const float* __restrict__ pmax, const int* __restrict__ phist,
                                              const float* __restrict__ w1, const float* __restrict__ b1,
                                              const float* __restrict__ w2, const float* __restrict__ b2,
                                              const float* __restrict__ w3, const float* __restrict__ b3,
                                              float* __restrict__ out) {
  __shared__ float f[FIN + 1];
  __shared__ float t1[64];
  __shared__ float t2[32];
  int g = blockIdx.x, t = threadIdx.x;
  {
    float s1v = 0.f, s2v = 0.f;
#pragma unroll
    for (int r = 0; r < 8; ++r) {
      s1v += pg1[(g * 8 + r) * 64 + t];
      s2v += pg2[(g * 8 + r) * 64 + t];
    }
    f[t]      = s1v * (1.f / NPG);
    f[64 + t] = s2v * (1.f / NPG);
  }
  if (t < BINS) {
    int tot = 0;
#pragma unroll
    for (int r = 0; r < 8; ++r) tot += phist[(g * 8 + r) * BINS + t];
    f[2 * H + t] = (float)tot * (1.f / 262144.f);
  }
  if (t == 0) {
    float s = 0.f, ss = 0.f, mx = -2.f;
#pragma unroll
    for (int r = 0; r < 8; ++r) {
      s += psum[g * 8 + r];
      ss += psumsq[g * 8 + r];
      mx = fmaxf(mx, pmax[g * 8 + r]);
    }
    const float inv = 1.f / 262144.f;
    float mean = s * inv;
    float var = fmaxf(ss * inv - mean * mean, 0.f);
    f[144] = mean;
    f[145] = mx;
    f[146] = sqrtf(var);
  }
  __syncthreads();
  float acc = b1[t];
  for (int k = 0; k < FIN; ++k) acc = fmaf(f[k], w1[k * 64 + t], acc);
  t1[t] = fmaxf(acc, 0.f);
  __syncthreads();
  if (t < 32) {
    float a2 = b2[t];
#pragma unroll 8
    for (int k = 0; k < 64; ++k) a2 = fmaf(t1[k], w2[k * 32 + t], a2);
    t2[t] = fmaxf(a2, 0.f);
  }
  __syncthreads();
  if (t == 0) {
    float a3 = b3[0];
#pragma unroll
    for (int k = 0; k < 32; ++k) a3 = fmaf(t2[k], w3[k], a3);
    out[g] = a3;
  }
}

}  // namespace

extern "C" void kernel_launch(void* const* d_in, const int* in_sizes, int n_in, void* d_out, int out_size,
                              void* d_ws, size_t ws_size, hipStream_t stream) {
  const float* x1 = (const float*)d_in[0];
  const int* e1 = (const int*)d_in[1];
  const float* x2 = (const float*)d_in[3];
  const int* e2 = (const int*)d_in[4];
  const float* enc_w1 = (const float*)d_in[6];
  const float* enc_b1 = (const float*)d_in[7];
  const float* enc_w2 = (const float*)d_in[8];
  const float* enc_b2 = (const float*)d_in[9];
  const float* enc_w3 = (const float*)d_in[10];
  const float* enc_b3 = (const float*)d_in[11];
  const float* enc_w4 = (const float*)d_in[12];
  const float* enc_b4 = (const float*)d_in[13];
  const float* mw1 = (const float*)d_in[14];
  const float* mb1 = (const float*)d_in[15];
  const float* mw2 = (const float*)d_in[16];
  const float* mb2 = (const float*)d_in[17];
  const float* mw3 = (const float*)d_in[18];
  const float* mb3 = (const float*)d_in[19];
  float* out = (float*)d_out;

  char* wsc = (char*)d_ws;
  size_t off = 0;
  auto alloc = [&](size_t bytes) -> void* {
    void* p = wsc + off;
    off += (bytes + 255) & ~(size_t)255;
    return p;
  };
  float* bufA = (float*)alloc((size_t)N * H * 4);   // 16 MB
  float* bufB = (float*)alloc((size_t)N * H * 4);   // 16 MB
  float* Hs1 = (float*)alloc((size_t)N * H * 4);    // 16 MB
  float* Hs2 = (float*)alloc((size_t)N * H * 4);    // 16 MB
  int* rowptr = (int*)alloc((size_t)(N + 1) * 4);
  int* colidx = (int*)alloc((size_t)E * 4);         // 4 MB
  int* cnt = (int*)alloc((size_t)N * 4);
  int* bsum = (int*)alloc(256 * 4);
  int* boff = (int*)alloc(256 * 4);
  float* pg1 = (float*)alloc((size_t)B * 8 * 64 * 4);
  float* pg2 = (float*)alloc((size_t)B * 8 * 64 * 4);
  float* psum = (float*)alloc(1024 * 4);
  float* psumsq = (float*)alloc(1024 * 4);
  float* pmaxa = (float*)alloc(1024 * 4);
  int* phist = (int*)alloc((size_t)1024 * BINS * 4);
  (void)ws_size;
  (void)in_sizes;
  (void)n_in;
  (void)out_size;

  auto build_csr = [&](const int* e) {
    const int* src = e;
    const int* dst = e + E;
    hipMemsetAsync(cnt, 0, (size_t)N * 4, stream);
    k_count<<<2048, 256, 0, stream>>>(dst, cnt);
    k_reduce256<<<256, 256, 0, stream>>>(cnt, bsum);
    k_scan256<<<1, 256, 0, stream>>>(bsum, boff);
    k_scanfin<<<256, 256, 0, stream>>>(cnt, boff, rowptr);
    hipMemsetAsync(cnt, 0, (size_t)N * 4, stream);
    k_fill<<<2048, 256, 0, stream>>>(src, dst, rowptr, cnt, colidx);
  };
  auto encode = [&](const float* x, float* Hout) {
    // layer1: y = x@W1 ; t = relu(y + segsum(y) + b1); h1 = relu(t@W2+b2); z = h1@W3
    k_xw<<<1024, 256, 0, stream>>>(x, enc_w1, bufA);
    k_fused<true><<<1024, 256, 0, stream>>>(bufA, rowptr, colidx, enc_b1, enc_w2, enc_b2, enc_w3, bufB);
    // layer2: t2 = relu(z + segsum(z) + b3); h2 = relu(t2@W4+b4)
    k_fused<false><<<1024, 256, 0, stream>>>(bufB, rowptr, colidx, enc_b3, enc_w4, enc_b4, nullptr, Hout);
  };

  build_csr(e1);
  encode(x1, Hs1);
  k_poolnorm<<<B * 8, 256, 0, stream>>>(Hs1, pg1);

  build_csr(e2);
  encode(x2, Hs2);
  k_poolnorm<<<B * 8, 256, 0, stream>>>(Hs2, pg2);

  k_sim<<<B * 8, 256, 0, stream>>>(Hs1, Hs2, psum, psumsq, pmaxa, phist);
  k_final<<<B, 64, 0, stream>>>(pg1, pg2, psum, psumsq, pmaxa, phist, mw1, mb1, mw2, mb2, mw3, mb3, out);
}

// Round 2
// 698.974 us; speedup vs baseline: 1.5964x; 1.5964x over previous
//
#include <hip/hip_runtime.h>
#include <hip/hip_bf16.h>

namespace {

constexpr int N    = 65536;
constexpr int E    = 1048576;
constexpr int B    = 128;
constexpr int NPG  = 512;
constexpr int IN   = 128;
constexpr int H    = 64;
constexpr int BINS = 16;
constexpr int FIN  = 2 * H + BINS + 3;  // 147

// ---------------- CSR build (by dst) ----------------

__global__ __launch_bounds__(256) void k_count(const int* __restrict__ dst, int* __restrict__ cnt) {
  for (int e = blockIdx.x * 256 + threadIdx.x; e < E; e += gridDim.x * 256)
    atomicAdd(&cnt[dst[e]], 1);
}

__global__ __launch_bounds__(256) void k_reduce256(const int* __restrict__ cnt, int* __restrict__ bsum) {
  __shared__ int s[256];
  int t = threadIdx.x;
  s[t] = cnt[blockIdx.x * 256 + t];
  __syncthreads();
  for (int d = 128; d > 0; d >>= 1) {
    if (t < d) s[t] += s[t + d];
    __syncthreads();
  }
  if (t == 0) bsum[blockIdx.x] = s[0];
}

__global__ __launch_bounds__(256) void k_scan256(const int* __restrict__ bsum, int* __restrict__ boff) {
  __shared__ int s[256];
  int t = threadIdx.x;
  int v = bsum[t];
  s[t] = v;
  __syncthreads();
  for (int d = 1; d < 256; d <<= 1) {
    int add = (t >= d) ? s[t - d] : 0;
    __syncthreads();
    s[t] += add;
    __syncthreads();
  }
  boff[t] = s[t] - v;  // exclusive
}

__global__ __launch_bounds__(256) void k_scanfin(const int* __restrict__ cnt, const int* __restrict__ boff,
                                                 int* __restrict__ rowptr) {
  __shared__ int s[256];
  int b = blockIdx.x, t = threadIdx.x;
  int idx = b * 256 + t;
  int v = cnt[idx];
  s[t] = v;
  __syncthreads();
  for (int d = 1; d < 256; d <<= 1) {
    int add = (t >= d) ? s[t - d] : 0;
    __syncthreads();
    s[t] += add;
    __syncthreads();
  }
  rowptr[idx] = boff[b] + s[t] - v;
  if (idx == N - 1) rowptr[N] = boff[b] + s[t];
}

__global__ __launch_bounds__(256) void k_fill(const int* __restrict__ src, const int* __restrict__ dst,
                                              const int* __restrict__ rowptr, int* __restrict__ cur,
                                              int* __restrict__ col) {
  for (int e = blockIdx.x * 256 + threadIdx.x; e < E; e += gridDim.x * 256) {
    int d = dst[e];
    int pos = rowptr[d] + atomicAdd(&cur[d], 1);
    col[pos] = src[e];
  }
}

// ---------------- gather: out[n] = relu(in[n] + sum_{j->n} in[j] + bias) ----------------
// One wave per node; 16 edges per batch -> 16 independent 256B row loads in flight.

__global__ __launch_bounds__(256) void k_gather(const float* __restrict__ in, const int* __restrict__ rowptr,
                                                const int* __restrict__ col, const float* __restrict__ bias,
                                                float* __restrict__ out) {
  int tid = threadIdx.x, lane = tid & 63, sub = tid >> 6;
  int n = blockIdx.x * 4 + sub;
  int p0 = rowptr[n], p1 = rowptr[n + 1];
  float a = in[(size_t)n * H + lane] + bias[lane];
  int p = p0;
  for (; p + 16 <= p1; p += 16) {
    int myc = (lane < 16) ? col[p + lane] : 0;
    float v[16];
#pragma unroll
    for (int i = 0; i < 16; ++i) {
      int c = __shfl(myc, i, 64);
      v[i] = in[(size_t)c * H + lane];
    }
#pragma unroll
    for (int i = 0; i < 16; ++i) a += v[i];
  }
  if (p < p1) {
    int cnt = p1 - p;
    int myc = (lane < 16 && p + lane < p1) ? col[p + lane] : 0;
#pragma unroll
    for (int i = 0; i < 16; ++i) {
      if (i < cnt) {
        int c = __shfl(myc, i, 64);
        a += in[(size_t)c * H + lane];
      }
    }
  }
  out[(size_t)n * H + lane] = fmaxf(a, 0.f);
}

// ---------------- dense helpers ----------------

__device__ __forceinline__ void fma8(float (&acc)[8], const float* p, float wv) {
  float4 lo = *(const float4*)(p);
  float4 hi = *(const float4*)(p + 4);
  acc[0] = fmaf(lo.x, wv, acc[0]);
  acc[1] = fmaf(lo.y, wv, acc[1]);
  acc[2] = fmaf(lo.z, wv, acc[2]);
  acc[3] = fmaf(lo.w, wv, acc[3]);
  acc[4] = fmaf(hi.x, wv, acc[4]);
  acc[5] = fmaf(hi.y, wv, acc[5]);
  acc[6] = fmaf(hi.z, wv, acc[6]);
  acc[7] = fmaf(hi.w, wv, acc[7]);
}

// y = x @ W ; x:[N,IN] W:[IN,H]. One 32-node tile per block, 8 nodes per wave.
__global__ __launch_bounds__(256) void k_xw(const float* __restrict__ x, const float* __restrict__ W,
                                            float* __restrict__ y) {
  __shared__ float sW[IN * H];                     // 32 KB
  __shared__ __align__(16) float sx[4][IN][8];     // 16 KB
  int tid = threadIdx.x, lane = tid & 63, sub = tid >> 6;
  for (int i = tid; i < IN * H; i += 256) sW[i] = W[i];
  __syncthreads();
  int nbase = blockIdx.x * 32 + sub * 8;
#pragma unroll
  for (int nd = 0; nd < 8; ++nd) {
    const float* xr = x + (size_t)(nbase + nd) * IN;
    sx[sub][lane][nd]      = xr[lane];
    sx[sub][lane + 64][nd] = xr[lane + 64];
  }
  // same-wave LDS producer/consumer: no barrier needed
  float acc[8];
#pragma unroll
  for (int nd = 0; nd < 8; ++nd) acc[nd] = 0.f;
  for (int k = 0; k < IN; ++k) fma8(acc, &sx[sub][k][0], sW[k * H + lane]);
#pragma unroll
  for (int nd = 0; nd < 8; ++nd) y[(size_t)(nbase + nd) * H + lane] = acc[nd];
}

// out = relu(in@Wa + ba) @ Wb   (dense middle of layer 1, fused with next layer's projection)
__global__ __launch_bounds__(256) void k_mid(const float* __restrict__ in, const float* __restrict__ Wa,
                                             const float* __restrict__ ba, const float* __restrict__ Wb,
                                             float* __restrict__ out) {
  __shared__ float sWa[H * H];                     // 16 KB
  __shared__ float sWb[H * H];                     // 16 KB
  __shared__ __align__(16) float st[4][H][8];      // 8 KB
  int tid = threadIdx.x, lane = tid & 63, sub = tid >> 6;
  for (int i = tid; i < H * H; i += 256) sWa[i] = Wa[i];
  for (int i = tid; i < H * H; i += 256) sWb[i] = Wb[i];
  float biasA = ba[lane];
  __syncthreads();
  int nbase = blockIdx.x * 32 + sub * 8;
#pragma unroll
  for (int nd = 0; nd < 8; ++nd) st[sub][lane][nd] = in[(size_t)(nbase + nd) * H + lane];
  float acc[8];
#pragma unroll
  for (int nd = 0; nd < 8; ++nd) acc[nd] = biasA;
  for (int k = 0; k < H; ++k) fma8(acc, &st[sub][k][0], sWa[k * H + lane]);
#pragma unroll
  for (int nd = 0; nd < 8; ++nd) st[sub][lane][nd] = fmaxf(acc[nd], 0.f);
  float acc2[8];
#pragma unroll
  for (int nd = 0; nd < 8; ++nd) acc2[nd] = 0.f;
  for (int k = 0; k < H; ++k) fma8(acc2, &st[sub][k][0], sWb[k * H + lane]);
#pragma unroll
  for (int nd = 0; nd < 8; ++nd) out[(size_t)(nbase + nd) * H + lane] = acc2[nd];
}

// h = relu(in@Wa + ba); write L2-normalized h; write per-32-node-tile pool partial sums of h.
__global__ __launch_bounds__(256) void k_last(const float* __restrict__ in, const float* __restrict__ Wa,
                                              const float* __restrict__ ba, float* __restrict__ outn,
                                              float* __restrict__ pg) {
  __shared__ float sWa[H * H];                     // 16 KB
  __shared__ __align__(16) float st[4][H][8];      // 8 KB
  __shared__ float sacc[4][64];
  int tid = threadIdx.x, lane = tid & 63, sub = tid >> 6;
  for (int i = tid; i < H * H; i += 256) sWa[i] = Wa[i];
  float biasA = ba[lane];
  __syncthreads();
  int nbase = blockIdx.x * 32 + sub * 8;
#pragma unroll
  for (int nd = 0; nd < 8; ++nd) st[sub][lane][nd] = in[(size_t)(nbase + nd) * H + lane];
  float acc[8];
#pragma unroll
  for (int nd = 0; nd < 8; ++nd) acc[nd] = biasA;
  for (int k = 0; k < H; ++k) fma8(acc, &st[sub][k][0], sWa[k * H + lane]);
  float psum = 0.f;
#pragma unroll
  for (int nd = 0; nd < 8; ++nd) {
    float h = fmaxf(acc[nd], 0.f);
    psum += h;
    float ss = h * h;
#pragma unroll
    for (int d = 1; d < 64; d <<= 1) ss += __shfl_xor(ss, d, 64);
    outn[(size_t)(nbase + nd) * H + lane] = h / fmaxf(sqrtf(ss), 1e-12f);
  }
  sacc[sub][lane] = psum;
  __syncthreads();
  if (sub == 0) pg[blockIdx.x * 64 + lane] = sacc[0][lane] + sacc[1][lane] + sacc[2][lane] + sacc[3][lane];
}

// ---------------- fused sim + hist + stats ----------------
__global__ __launch_bounds__(256) void k_sim(const float* __restrict__ H1n, const float* __restrict__ H2n,
                                             float* __restrict__ psum, float* __restrict__ psumsq,
                                             float* __restrict__ pmax, int* __restrict__ phist) {
  __shared__ float s1[64][65];
  __shared__ float s2[128][65];
  __shared__ int shist[64 * 17];
  __shared__ float sred[256];
  int tid = threadIdx.x;
  int g = blockIdx.x >> 3, rt = blockIdx.x & 7;
  for (int i = tid; i < 64 * 17; i += 256) shist[i] = 0;
  const float* base1 = H1n + ((size_t)g * NPG + rt * 64) * H;
  for (int i = tid; i < 64 * 64; i += 256) s1[i >> 6][i & 63] = base1[i];
  int ty = tid >> 4, tx = tid & 15;
  int rep = (tid & 63) * 17;
  float lmax = -2.f, lsum = 0.f, lsumsq = 0.f;
  for (int ch = 0; ch < 4; ++ch) {
    __syncthreads();
    const float* base2 = H2n + ((size_t)g * NPG + ch * 128) * H;
    for (int i = tid; i < 128 * 64; i += 256) s2[i >> 6][i & 63] = base2[i];
    __syncthreads();
    float acc[4][8];
#pragma unroll
    for (int i = 0; i < 4; ++i)
#pragma unroll
      for (int j = 0; j < 8; ++j) acc[i][j] = 0.f;
    for (int k = 0; k < 64; ++k) {
      float a[4], b[8];
#pragma unroll
      for (int i = 0; i < 4; ++i) a[i] = s1[ty + 16 * i][k];
#pragma unroll
      for (int j = 0; j < 8; ++j) b[j] = s2[tx + 16 * j][k];
#pragma unroll
      for (int i = 0; i < 4; ++i)
#pragma unroll
        for (int j = 0; j < 8; ++j) acc[i][j] = fmaf(a[i], b[j], acc[i][j]);
    }
#pragma unroll
    for (int i = 0; i < 4; ++i)
#pragma unroll
      for (int j = 0; j < 8; ++j) {
        float v = acc[i][j];
        lmax = fmaxf(lmax, v);
        lsum += v;
        lsumsq = fmaf(v, v, lsumsq);
        int bin = (int)floorf((v + 1.f) * 8.f);
        bin = bin < 0 ? 0 : (bin > BINS - 1 ? BINS - 1 : bin);
        atomicAdd(&shist[rep + bin], 1);
      }
  }
  sred[tid] = lsum;
  __syncthreads();
  for (int w = 128; w > 0; w >>= 1) {
    if (tid < w) sred[tid] += sred[tid + w];
    __syncthreads();
  }
  if (tid == 0) psum[blockIdx.x] = sred[0];
  __syncthreads();
  sred[tid] = lsumsq;
  __syncthreads();
  for (int w = 128; w > 0; w >>= 1) {
    if (tid < w) sred[tid] += sred[tid + w];
    __syncthreads();
  }
  if (tid == 0) psumsq[blockIdx.x] = sred[0];
  __syncthreads();
  sred[tid] = lmax;
  __syncthreads();
  for (int w = 128; w > 0; w >>= 1) {
    if (tid < w) sred[tid] = fmaxf(sred[tid], sred[tid + w]);
    __syncthreads();
  }
  if (tid == 0) pmax[blockIdx.x] = sred[0];
  __syncthreads();
  if (tid < BINS) {
    int tot = 0;
    for (int r = 0; r < 64; ++r) tot += shist[r * 17 + tid];
    phist[blockIdx.x * BINS + tid] = tot;
  }
}

// ---------------- final feature assembly + MLP ----------------
__global__ __launch_bounds__(64) void k_final(const float* __restrict__ pg1, const float* __restrict__ pg2,
                                              const float* __restrict__ psum, const float* __restrict__ psumsq,
                                              const float* __restrict__ pmax, const int* __restrict__ phist,
                                              const float* __restrict__ w1, const float* __restrict__ b1,
                                              const float* __restrict__ w2, const float* __restrict__ b2,
                                              const float* __restrict__ w3, const float* __restrict__ b3,
                                              float* __restrict__ out) {
  __shared__ float f[FIN + 1];
  __shared__ float t1[64];
  __shared__ float t2[32];
  int g = blockIdx.x, t = threadIdx.x;
  {
    float s1v = 0.f, s2v = 0.f;
#pragma unroll
    for (int r = 0; r < 16; ++r) {
      s1v += pg1[(g * 16 + r) * 64 + t];
      s2v += pg2[(g * 16 + r) * 64 + t];
    }
    f[t]      = s1v * (1.f / NPG);
    f[64 + t] = s2v * (1.f / NPG);
  }
  if (t < BINS) {
    int tot = 0;
#pragma unroll
    for (int r = 0; r < 8; ++r) tot += phist[(g * 8 + r) * BINS + t];
    f[2 * H + t] = (float)tot * (1.f / 262144.f);
  }
  if (t == 0) {
    float s = 0.f, ss = 0.f, mx = -2.f;
#pragma unroll
    for (int r = 0; r < 8; ++r) {
      s += psum[g * 8 + r];
      ss += psumsq[g * 8 + r];
      mx = fmaxf(mx, pmax[g * 8 + r]);
    }
    const float inv = 1.f / 262144.f;
    float mean = s * inv;
    float var = fmaxf(ss * inv - mean * mean, 0.f);
    f[144] = mean;
    f[145] = mx;
    f[146] = sqrtf(var);
  }
  __syncthreads();
  float acc = b1[t];
  for (int k = 0; k < FIN; ++k) acc = fmaf(f[k], w1[k * 64 + t], acc);
  t1[t] = fmaxf(acc, 0.f);
  __syncthreads();
  if (t < 32) {
    float a2 = b2[t];
#pragma unroll 8
    for (int k = 0; k < 64; ++k) a2 = fmaf(t1[k], w2[k * 32 + t], a2);
    t2[t] = fmaxf(a2, 0.f);
  }
  __syncthreads();
  if (t == 0) {
    float a3 = b3[0];
#pragma unroll
    for (int k = 0; k < 32; ++k) a3 = fmaf(t2[k], w3[k], a3);
    out[g] = a3;
  }
}

}  // namespace

extern "C" void kernel_launch(void* const* d_in, const int* in_sizes, int n_in, void* d_out, int out_size,
                              void* d_ws, size_t ws_size, hipStream_t stream) {
  const float* x1 = (const float*)d_in[0];
  const int* e1 = (const int*)d_in[1];
  const float* x2 = (const float*)d_in[3];
  const int* e2 = (const int*)d_in[4];
  const float* enc_w1 = (const float*)d_in[6];
  const float* enc_b1 = (const float*)d_in[7];
  const float* enc_w2 = (const float*)d_in[8];
  const float* enc_b2 = (const float*)d_in[9];
  const float* enc_w3 = (const float*)d_in[10];
  const float* enc_b3 = (const float*)d_in[11];
  const float* enc_w4 = (const float*)d_in[12];
  const float* enc_b4 = (const float*)d_in[13];
  const float* mw1 = (const float*)d_in[14];
  const float* mb1 = (const float*)d_in[15];
  const float* mw2 = (const float*)d_in[16];
  const float* mb2 = (const float*)d_in[17];
  const float* mw3 = (const float*)d_in[18];
  const float* mb3 = (const float*)d_in[19];
  float* out = (float*)d_out;

  char* wsc = (char*)d_ws;
  size_t off = 0;
  auto alloc = [&](size_t bytes) -> void* {
    void* p = wsc + off;
    off += (bytes + 255) & ~(size_t)255;
    return p;
  };
  float* bufA = (float*)alloc((size_t)N * H * 4);   // 16 MB
  float* bufB = (float*)alloc((size_t)N * H * 4);   // 16 MB
  float* Hs1 = (float*)alloc((size_t)N * H * 4);    // 16 MB
  float* Hs2 = (float*)alloc((size_t)N * H * 4);    // 16 MB
  int* rowptr = (int*)alloc((size_t)(N + 1) * 4);
  int* colidx = (int*)alloc((size_t)E * 4);         // 4 MB
  int* cnt = (int*)alloc((size_t)N * 4);
  int* bsum = (int*)alloc(256 * 4);
  int* boff = (int*)alloc(256 * 4);
  float* pg1 = (float*)alloc((size_t)(N / 32) * 64 * 4);  // 512 KB
  float* pg2 = (float*)alloc((size_t)(N / 32) * 64 * 4);
  float* psum = (float*)alloc(1024 * 4);
  float* psumsq = (float*)alloc(1024 * 4);
  float* pmaxa = (float*)alloc(1024 * 4);
  int* phist = (int*)alloc((size_t)1024 * BINS * 4);
  (void)ws_size;
  (void)in_sizes;
  (void)n_in;
  (void)out_size;

  auto build_csr = [&](const int* e) {
    const int* src = e;
    const int* dst = e + E;
    hipMemsetAsync(cnt, 0, (size_t)N * 4, stream);
    k_count<<<2048, 256, 0, stream>>>(dst, cnt);
    k_reduce256<<<256, 256, 0, stream>>>(cnt, bsum);
    k_scan256<<<1, 256, 0, stream>>>(bsum, boff);
    k_scanfin<<<256, 256, 0, stream>>>(cnt, boff, rowptr);
    hipMemsetAsync(cnt, 0, (size_t)N * 4, stream);
    k_fill<<<2048, 256, 0, stream>>>(src, dst, rowptr, cnt, colidx);
  };
  auto encode = [&](const float* x, float* Hn, float* pg) {
    // layer1: y = x@W1 ; t1 = relu(y + agg(y) + b1); z = relu(t1@W2+b2)@W3
    k_xw<<<N / 32, 256, 0, stream>>>(x, enc_w1, bufA);
    k_gather<<<N / 4, 256, 0, stream>>>(bufA, rowptr, colidx, enc_b1, bufB);
    k_mid<<<N / 32, 256, 0, stream>>>(bufB, enc_w2, enc_b2, enc_w3, bufA);
    // layer2: t2 = relu(z + agg(z) + b3); h = relu(t2@W4+b4); normalize+pool
    k_gather<<<N / 4, 256, 0, stream>>>(bufA, rowptr, colidx, enc_b3, bufB);
    k_last<<<N / 32, 256, 0, stream>>>(bufB, enc_w4, enc_b4, Hn, pg);
  };

  build_csr(e1);
  encode(x1, Hs1, pg1);

  build_csr(e2);
  encode(x2, Hs2, pg2);

  k_sim<<<B * 8, 256, 0, stream>>>(Hs1, Hs2, psum, psumsq, pmaxa, phist);
  k_final<<<B, 64, 0, stream>>>(pg1, pg2, psum, psumsq, pmaxa, phist, mw1, mb1, mw2, mb2, mw3, mb3, out);
}

// Round 3
// 632.283 us; speedup vs baseline: 1.7648x; 1.1055x over previous
//
#include <hip/hip_runtime.h>
#include <hip/hip_bf16.h>

namespace {

constexpr int N    = 65536;
constexpr int E    = 1048576;
constexpr int N2   = 2 * N;      // both sides concatenated
constexpr int B    = 128;
constexpr int NPG  = 512;
constexpr int IN   = 128;
constexpr int H    = 64;
constexpr int BINS = 16;
constexpr int FIN  = 2 * H + BINS + 3;  // 147

// ---------------- combined CSR build over 2N nodes ----------------

__global__ __launch_bounds__(256) void k_count(const int* __restrict__ dst1, const int* __restrict__ dst2,
                                               int* __restrict__ cnt) {
  int b = blockIdx.x;
  const int* d = (b < 2048) ? dst1 : dst2;
  int off = (b < 2048) ? 0 : N;
  for (int e = (b & 2047) * 256 + threadIdx.x; e < E; e += 2048 * 256)
    atomicAdd(&cnt[off + d[e]], 1);
}

__global__ __launch_bounds__(256) void k_reduce256(const int* __restrict__ cnt, int* __restrict__ bsum) {
  __shared__ int s[256];
  int t = threadIdx.x;
  s[t] = cnt[blockIdx.x * 256 + t];
  __syncthreads();
  for (int d = 128; d > 0; d >>= 1) {
    if (t < d) s[t] += s[t + d];
    __syncthreads();
  }
  if (t == 0) bsum[blockIdx.x] = s[0];
}

__global__ __launch_bounds__(512) void k_scan512(const int* __restrict__ bsum, int* __restrict__ boff) {
  __shared__ int s[512];
  int t = threadIdx.x;
  int v = bsum[t];
  s[t] = v;
  __syncthreads();
  for (int d = 1; d < 512; d <<= 1) {
    int add = (t >= d) ? s[t - d] : 0;
    __syncthreads();
    s[t] += add;
    __syncthreads();
  }
  boff[t] = s[t] - v;  // exclusive
}

__global__ __launch_bounds__(256) void k_scanfin(const int* __restrict__ cnt, const int* __restrict__ boff,
                                                 int* __restrict__ rowptr) {
  __shared__ int s[256];
  int b = blockIdx.x, t = threadIdx.x;
  int idx = b * 256 + t;
  int v = cnt[idx];
  s[t] = v;
  __syncthreads();
  for (int d = 1; d < 256; d <<= 1) {
    int add = (t >= d) ? s[t - d] : 0;
    __syncthreads();
    s[t] += add;
    __syncthreads();
  }
  rowptr[idx] = boff[b] + s[t] - v;
  if (idx == N2 - 1) rowptr[N2] = boff[b] + s[t];
}

__global__ __launch_bounds__(256) void k_fill(const int* __restrict__ src1, const int* __restrict__ dst1,
                                              const int* __restrict__ src2, const int* __restrict__ dst2,
                                              const int* __restrict__ rowptr, int* __restrict__ cur,
                                              int* __restrict__ col) {
  int b = blockIdx.x;
  const int* s = (b < 2048) ? src1 : src2;
  const int* d = (b < 2048) ? dst1 : dst2;
  int off = (b < 2048) ? 0 : N;
  for (int e = (b & 2047) * 256 + threadIdx.x; e < E; e += 2048 * 256) {
    int dd = off + d[e];
    int pos = rowptr[dd] + atomicAdd(&cur[dd], 1);
    col[pos] = off + s[e];
  }
}

// ---------------- gather: out[n] = relu(in[n] + sum_{j->n} in[j] + bias) ----------------

__global__ __launch_bounds__(256) void k_gather(const float* __restrict__ in, const int* __restrict__ rowptr,
                                                const int* __restrict__ col, const float* __restrict__ bias,
                                                float* __restrict__ out) {
  int tid = threadIdx.x, lane = tid & 63, sub = tid >> 6;
  int n = blockIdx.x * 4 + sub;
  int p0 = rowptr[n], p1 = rowptr[n + 1];
  float a = in[(size_t)n * H + lane] + bias[lane];
  int p = p0;
  for (; p + 16 <= p1; p += 16) {
    int myc = (lane < 16) ? col[p + lane] : 0;
    float v[16];
#pragma unroll
    for (int i = 0; i < 16; ++i) {
      int c = __shfl(myc, i, 64);
      v[i] = in[(size_t)c * H + lane];
    }
#pragma unroll
    for (int i = 0; i < 16; ++i) a += v[i];
  }
  if (p < p1) {
    int cnt = p1 - p;
    int myc = (lane < 16 && p + lane < p1) ? col[p + lane] : 0;
#pragma unroll
    for (int i = 0; i < 16; ++i) {
      if (i < cnt) {
        int c = __shfl(myc, i, 64);
        a += in[(size_t)c * H + lane];
      }
    }
  }
  out[(size_t)n * H + lane] = fmaxf(a, 0.f);
}

// ---------------- dense helpers ----------------

__device__ __forceinline__ void fma8(float (&acc)[8], const float* p, float wv) {
  float4 lo = *(const float4*)(p);
  float4 hi = *(const float4*)(p + 4);
  acc[0] = fmaf(lo.x, wv, acc[0]);
  acc[1] = fmaf(lo.y, wv, acc[1]);
  acc[2] = fmaf(lo.z, wv, acc[2]);
  acc[3] = fmaf(lo.w, wv, acc[3]);
  acc[4] = fmaf(hi.x, wv, acc[4]);
  acc[5] = fmaf(hi.y, wv, acc[5]);
  acc[6] = fmaf(hi.z, wv, acc[6]);
  acc[7] = fmaf(hi.w, wv, acc[7]);
}

// y = x @ W over 2N nodes; x selected per side. One 32-node tile per block.
__global__ __launch_bounds__(256) void k_xw(const float* __restrict__ x1, const float* __restrict__ x2,
                                            const float* __restrict__ W, float* __restrict__ y) {
  __shared__ float sW[IN * H];
  __shared__ __align__(16) float sx[4][IN][8];
  int tid = threadIdx.x, lane = tid & 63, sub = tid >> 6;
  for (int i = tid; i < IN * H; i += 256) sW[i] = W[i];
  __syncthreads();
  int nbase = blockIdx.x * 32 + sub * 8;
  const float* xp = (nbase < N) ? (x1 + (size_t)nbase * IN) : (x2 + (size_t)(nbase - N) * IN);
#pragma unroll
  for (int nd = 0; nd < 8; ++nd) {
    const float* xr = xp + (size_t)nd * IN;
    sx[sub][lane][nd]      = xr[lane];
    sx[sub][lane + 64][nd] = xr[lane + 64];
  }
  // same-wave LDS producer/consumer (DS ops complete in order): no barrier
  float acc[8];
#pragma unroll
  for (int nd = 0; nd < 8; ++nd) acc[nd] = 0.f;
  for (int k = 0; k < IN; ++k) fma8(acc, &sx[sub][k][0], sW[k * H + lane]);
#pragma unroll
  for (int nd = 0; nd < 8; ++nd) y[(size_t)(nbase + nd) * H + lane] = acc[nd];
}

// out = relu(in@Wa + ba) @ Wb
__global__ __launch_bounds__(256) void k_mid(const float* __restrict__ in, const float* __restrict__ Wa,
                                             const float* __restrict__ ba, const float* __restrict__ Wb,
                                             float* __restrict__ out) {
  __shared__ float sWa[H * H];
  __shared__ float sWb[H * H];
  __shared__ __align__(16) float st[4][H][8];
  int tid = threadIdx.x, lane = tid & 63, sub = tid >> 6;
  for (int i = tid; i < H * H; i += 256) sWa[i] = Wa[i];
  for (int i = tid; i < H * H; i += 256) sWb[i] = Wb[i];
  float biasA = ba[lane];
  __syncthreads();
  int nbase = blockIdx.x * 32 + sub * 8;
#pragma unroll
  for (int nd = 0; nd < 8; ++nd) st[sub][lane][nd] = in[(size_t)(nbase + nd) * H + lane];
  float acc[8];
#pragma unroll
  for (int nd = 0; nd < 8; ++nd) acc[nd] = biasA;
  for (int k = 0; k < H; ++k) fma8(acc, &st[sub][k][0], sWa[k * H + lane]);
#pragma unroll
  for (int nd = 0; nd < 8; ++nd) st[sub][lane][nd] = fmaxf(acc[nd], 0.f);
  float acc2[8];
#pragma unroll
  for (int nd = 0; nd < 8; ++nd) acc2[nd] = 0.f;
  for (int k = 0; k < H; ++k) fma8(acc2, &st[sub][k][0], sWb[k * H + lane]);
#pragma unroll
  for (int nd = 0; nd < 8; ++nd) out[(size_t)(nbase + nd) * H + lane] = acc2[nd];
}

// h = relu(in@Wa + ba); write L2-normalized h; write per-32-node-tile pool partials.
__global__ __launch_bounds__(256) void k_last(const float* __restrict__ in, const float* __restrict__ Wa,
                                              const float* __restrict__ ba, float* __restrict__ outn,
                                              float* __restrict__ pg) {
  __shared__ float sWa[H * H];
  __shared__ __align__(16) float st[4][H][8];
  __shared__ float sacc[4][64];
  int tid = threadIdx.x, lane = tid & 63, sub = tid >> 6;
  for (int i = tid; i < H * H; i += 256) sWa[i] = Wa[i];
  float biasA = ba[lane];
  __syncthreads();
  int nbase = blockIdx.x * 32 + sub * 8;
#pragma unroll
  for (int nd = 0; nd < 8; ++nd) st[sub][lane][nd] = in[(size_t)(nbase + nd) * H + lane];
  float acc[8];
#pragma unroll
  for (int nd = 0; nd < 8; ++nd) acc[nd] = biasA;
  for (int k = 0; k < H; ++k) fma8(acc, &st[sub][k][0], sWa[k * H + lane]);
  float psum = 0.f;
#pragma unroll
  for (int nd = 0; nd < 8; ++nd) {
    float h = fmaxf(acc[nd], 0.f);
    psum += h;
    float ss = h * h;
#pragma unroll
    for (int d = 1; d < 64; d <<= 1) ss += __shfl_xor(ss, d, 64);
    outn[(size_t)(nbase + nd) * H + lane] = h / fmaxf(sqrtf(ss), 1e-12f);
  }
  sacc[sub][lane] = psum;
  __syncthreads();
  if (sub == 0) pg[blockIdx.x * 64 + lane] = sacc[0][lane] + sacc[1][lane] + sacc[2][lane] + sacc[3][lane];
}

// ---------------- fused sim + hist + stats (float4 LDS, XOR swizzle) ----------------
// Block: (graph g, 64-row tile rt of side1) x full 512 cols of side2 in 4 chunks of 128.
// LDS layout: s[row][k4 ^ (row&15)] float4. Thread (ty,tx): rows ty+16i, cols tx+16j ->
// (row&15)==ty / ==tx, so the swizzle is one XOR per operand class per k4.
__global__ __launch_bounds__(256, 3) void k_sim(const float* __restrict__ Hn, float* __restrict__ psum,
                                                float* __restrict__ psumsq, float* __restrict__ pmax,
                                                int* __restrict__ phist) {
  __shared__ float4 s1[64 * 16];   // 16 KB
  __shared__ float4 s2[128 * 16];  // 32 KB
  __shared__ int shist[64 * 17];   // 4.25 KB, 64 replicas stride 17
  __shared__ float sfin[4][4];
  int tid = threadIdx.x;
  int g = blockIdx.x >> 3, rt = blockIdx.x & 7;
  for (int i = tid; i < 64 * 17; i += 256) shist[i] = 0;
  const float4* b1p = (const float4*)(Hn + ((size_t)g * NPG + rt * 64) * H);
  for (int i = tid; i < 1024; i += 256) {
    int row = i >> 4, k4 = i & 15;
    s1[(row << 4) | (k4 ^ (row & 15))] = b1p[i];
  }
  int ty = tid >> 4, tx = tid & 15;
  int rep = (tid & 63) * 17;
  float lmax = -2.f, lsum = 0.f, lsumsq = 0.f;
  const float* H2 = Hn + (size_t)N * H;
  for (int ch = 0; ch < 4; ++ch) {
    __syncthreads();
    const float4* b2p = (const float4*)(H2 + ((size_t)g * NPG + ch * 128) * H);
    for (int i = tid; i < 2048; i += 256) {
      int row = i >> 4, k4 = i & 15;
      s2[(row << 4) | (k4 ^ (row & 15))] = b2p[i];
    }
    __syncthreads();
    float acc[4][8];
#pragma unroll
    for (int i = 0; i < 4; ++i)
#pragma unroll
      for (int j = 0; j < 8; ++j) acc[i][j] = 0.f;
#pragma unroll 2
    for (int k4 = 0; k4 < 16; ++k4) {
      int ka = k4 ^ ty, kb = k4 ^ tx;
      float4 av[4], bv[8];
#pragma unroll
      for (int i = 0; i < 4; ++i) av[i] = s1[((ty + 16 * i) << 4) | ka];
#pragma unroll
      for (int j = 0; j < 8; ++j) bv[j] = s2[((tx + 16 * j) << 4) | kb];
#pragma unroll
      for (int i = 0; i < 4; ++i)
#pragma unroll
        for (int j = 0; j < 8; ++j) {
          acc[i][j] = fmaf(av[i].x, bv[j].x, acc[i][j]);
          acc[i][j] = fmaf(av[i].y, bv[j].y, acc[i][j]);
          acc[i][j] = fmaf(av[i].z, bv[j].z, acc[i][j]);
          acc[i][j] = fmaf(av[i].w, bv[j].w, acc[i][j]);
        }
    }
#pragma unroll
    for (int i = 0; i < 4; ++i)
#pragma unroll
      for (int j = 0; j < 8; ++j) {
        float v = acc[i][j];
        lmax = fmaxf(lmax, v);
        lsum += v;
        lsumsq = fmaf(v, v, lsumsq);
        int bin = (int)((v + 1.f) * 8.f);  // trunc == floor here (arg >= -eps); clamped below
        bin = bin < 0 ? 0 : (bin > BINS - 1 ? BINS - 1 : bin);
        atomicAdd(&shist[rep + bin], 1);
      }
  }
#pragma unroll
  for (int d = 1; d < 64; d <<= 1) {
    lsum += __shfl_xor(lsum, d, 64);
    lsumsq += __shfl_xor(lsumsq, d, 64);
    lmax = fmaxf(lmax, __shfl_xor(lmax, d, 64));
  }
  int wv = tid >> 6, lane = tid & 63;
  if (lane == 0) {
    sfin[wv][0] = lsum;
    sfin[wv][1] = lsumsq;
    sfin[wv][2] = lmax;
  }
  __syncthreads();
  if (tid == 0) {
    psum[blockIdx.x] = sfin[0][0] + sfin[1][0] + sfin[2][0] + sfin[3][0];
    psumsq[blockIdx.x] = sfin[0][1] + sfin[1][1] + sfin[2][1] + sfin[3][1];
    pmax[blockIdx.x] = fmaxf(fmaxf(sfin[0][2], sfin[1][2]), fmaxf(sfin[2][2], sfin[3][2]));
  }
  if (tid < BINS) {
    int tot = 0;
    for (int r = 0; r < 64; ++r) tot += shist[r * 17 + tid];
    phist[blockIdx.x * BINS + tid] = tot;
  }
}

// ---------------- final feature assembly + MLP ----------------
__global__ __launch_bounds__(64) void k_final(const float* __restrict__ pg1, const float* __restrict__ pg2,
                                              const float* __restrict__ psum, const float* __restrict__ psumsq,
                                              const float* __restrict__ pmax, const int* __restrict__ phist,
                                              const float* __restrict__ w1, const float* __restrict__ b1,
                                              const float* __restrict__ w2, const float* __restrict__ b2,
                                              const float* __restrict__ w3, const float* __restrict__ b3,
                                              float* __restrict__ out) {
  __shared__ float f[FIN + 1];
  __shared__ float t1[64];
  __shared__ float t2[32];
  int g = blockIdx.x, t = threadIdx.x;
  {
    float s1v = 0.f, s2v = 0.f;
#pragma unroll
    for (int r = 0; r < 16; ++r) {
      s1v += pg1[(g * 16 + r) * 64 + t];
      s2v += pg2[(g * 16 + r) * 64 + t];
    }
    f[t]      = s1v * (1.f / NPG);
    f[64 + t] = s2v * (1.f / NPG);
  }
  if (t < BINS) {
    int tot = 0;
#pragma unroll
    for (int r = 0; r < 8; ++r) tot += phist[(g * 8 + r) * BINS + t];
    f[2 * H + t] = (float)tot * (1.f / 262144.f);
  }
  if (t == 0) {
    float s = 0.f, ss = 0.f, mx = -2.f;
#pragma unroll
    for (int r = 0; r < 8; ++r) {
      s += psum[g * 8 + r];
      ss += psumsq[g * 8 + r];
      mx = fmaxf(mx, pmax[g * 8 + r]);
    }
    const float inv = 1.f / 262144.f;
    float mean = s * inv;
    float var = fmaxf(ss * inv - mean * mean, 0.f);
    f[144] = mean;
    f[145] = mx;
    f[146] = sqrtf(var);
  }
  __syncthreads();
  float acc = b1[t];
  for (int k = 0; k < FIN; ++k) acc = fmaf(f[k], w1[k * 64 + t], acc);
  t1[t] = fmaxf(acc, 0.f);
  __syncthreads();
  if (t < 32) {
    float a2 = b2[t];
#pragma unroll 8
    for (int k = 0; k < 64; ++k) a2 = fmaf(t1[k], w2[k * 32 + t], a2);
    t2[t] = fmaxf(a2, 0.f);
  }
  __syncthreads();
  if (t == 0) {
    float a3 = b3[0];
#pragma unroll
    for (int k = 0; k < 32; ++k) a3 = fmaf(t2[k], w3[k], a3);
    out[g] = a3;
  }
}

}  // namespace

extern "C" void kernel_launch(void* const* d_in, const int* in_sizes, int n_in, void* d_out, int out_size,
                              void* d_ws, size_t ws_size, hipStream_t stream) {
  const float* x1 = (const float*)d_in[0];
  const int* e1 = (const int*)d_in[1];
  const float* x2 = (const float*)d_in[3];
  const int* e2 = (const int*)d_in[4];
  const float* enc_w1 = (const float*)d_in[6];
  const float* enc_b1 = (const float*)d_in[7];
  const float* enc_w2 = (const float*)d_in[8];
  const float* enc_b2 = (const float*)d_in[9];
  const float* enc_w3 = (const float*)d_in[10];
  const float* enc_b3 = (const float*)d_in[11];
  const float* enc_w4 = (const float*)d_in[12];
  const float* enc_b4 = (const float*)d_in[13];
  const float* mw1 = (const float*)d_in[14];
  const float* mb1 = (const float*)d_in[15];
  const float* mw2 = (const float*)d_in[16];
  const float* mb2 = (const float*)d_in[17];
  const float* mw3 = (const float*)d_in[18];
  const float* mb3 = (const float*)d_in[19];
  float* out = (float*)d_out;

  char* wsc = (char*)d_ws;
  size_t off = 0;
  auto alloc = [&](size_t bytes) -> void* {
    void* p = wsc + off;
    off += (bytes + 255) & ~(size_t)255;
    return p;
  };
  float* bufA = (float*)alloc((size_t)N2 * H * 4);  // 32 MB (also final Hn)
  float* bufB = (float*)alloc((size_t)N2 * H * 4);  // 32 MB
  int* rowptr = (int*)alloc((size_t)(N2 + 1) * 4);
  int* colidx = (int*)alloc((size_t)2 * E * 4);     // 8 MB
  int* cnt = (int*)alloc((size_t)N2 * 4);
  int* bsum = (int*)alloc(512 * 4);
  int* boff = (int*)alloc(512 * 4);
  float* pg = (float*)alloc((size_t)(N2 / 32) * 64 * 4);  // 1 MB
  float* psum = (float*)alloc(1024 * 4);
  float* psumsq = (float*)alloc(1024 * 4);
  float* pmaxa = (float*)alloc(1024 * 4);
  int* phist = (int*)alloc((size_t)1024 * BINS * 4);
  (void)ws_size;
  (void)in_sizes;
  (void)n_in;
  (void)out_size;

  const int* src1 = e1;
  const int* dst1 = e1 + E;
  const int* src2 = e2;
  const int* dst2 = e2 + E;

  // combined CSR over 2N nodes
  hipMemsetAsync(cnt, 0, (size_t)N2 * 4, stream);
  k_count<<<4096, 256, 0, stream>>>(dst1, dst2, cnt);
  k_reduce256<<<512, 256, 0, stream>>>(cnt, bsum);
  k_scan512<<<1, 512, 0, stream>>>(bsum, boff);
  k_scanfin<<<512, 256, 0, stream>>>(cnt, boff, rowptr);
  hipMemsetAsync(cnt, 0, (size_t)N2 * 4, stream);
  k_fill<<<4096, 256, 0, stream>>>(src1, dst1, src2, dst2, rowptr, cnt, colidx);

  // encoder over 2N nodes: A -> B -> A -> B -> A(normalized)
  k_xw<<<N2 / 32, 256, 0, stream>>>(x1, x2, enc_w1, bufA);
  k_gather<<<N2 / 4, 256, 0, stream>>>(bufA, rowptr, colidx, enc_b1, bufB);
  k_mid<<<N2 / 32, 256, 0, stream>>>(bufB, enc_w2, enc_b2, enc_w3, bufA);
  k_gather<<<N2 / 4, 256, 0, stream>>>(bufA, rowptr, colidx, enc_b3, bufB);
  k_last<<<N2 / 32, 256, 0, stream>>>(bufB, enc_w4, enc_b4, bufA, pg);

  k_sim<<<B * 8, 256, 0, stream>>>(bufA, psum, psumsq, pmaxa, phist);
  k_final<<<B, 64, 0, stream>>>(pg, pg + (size_t)2048 * 64, psum, psumsq, pmaxa, phist, mw1, mb1, mw2, mb2,
                                mw3, mb3, out);
}

// Round 4
// 527.379 us; speedup vs baseline: 2.1158x; 1.1989x over previous
//
#include <hip/hip_runtime.h>
#include <hip/hip_bf16.h>

namespace {

constexpr int N    = 65536;
constexpr int E    = 1048576;
constexpr int N2   = 2 * N;      // both sides concatenated
constexpr int B    = 128;
constexpr int NPG  = 512;
constexpr int IN   = 128;
constexpr int H    = 64;
constexpr int BINS = 16;
constexpr int FIN  = 2 * H + BINS + 3;  // 147

// ---------------- fused: CSR count+rank (blocks 0..4095) + x@W1 (blocks 4096..8191) ----------------
// rank[e] = this edge's arrival order at its dst -> fill pass needs no atomics.

__global__ __launch_bounds__(256) void k_count_xw(const int* __restrict__ dst1, const int* __restrict__ dst2,
                                                  int* __restrict__ cnt, int* __restrict__ rank,
                                                  const float* __restrict__ x1, const float* __restrict__ x2,
                                                  const float* __restrict__ W, float* __restrict__ y) {
  __shared__ float sW[IN * H];                     // 32 KB
  __shared__ __align__(16) float sx[4][IN][8];     // 16 KB
  int b = blockIdx.x, tid = threadIdx.x;
  if (b < 4096) {
    const int* d = (b < 2048) ? dst1 : dst2;
    int off = (b < 2048) ? 0 : N;
    int rbase = (b < 2048) ? 0 : E;
    for (int e = (b & 2047) * 256 + tid; e < E; e += 2048 * 256)
      rank[rbase + e] = atomicAdd(&cnt[off + d[e]], 1);
  } else {
    int bx = b - 4096;
    int lane = tid & 63, sub = tid >> 6;
    for (int i = tid; i < IN * H; i += 256) sW[i] = W[i];
    __syncthreads();
    int nbase = bx * 32 + sub * 8;
    const float* xp = (nbase < N) ? (x1 + (size_t)nbase * IN) : (x2 + (size_t)(nbase - N) * IN);
#pragma unroll
    for (int nd = 0; nd < 8; ++nd) {
      const float* xr = xp + (size_t)nd * IN;
      sx[sub][lane][nd]      = xr[lane];
      sx[sub][lane + 64][nd] = xr[lane + 64];
    }
    // same-wave LDS producer/consumer: no barrier needed
    float acc[8];
#pragma unroll
    for (int nd = 0; nd < 8; ++nd) acc[nd] = 0.f;
    for (int k = 0; k < IN; ++k) {
      float wv = sW[k * H + lane];
      const float* p = &sx[sub][k][0];
      float4 lo = *(const float4*)(p);
      float4 hi = *(const float4*)(p + 4);
      acc[0] = fmaf(lo.x, wv, acc[0]); acc[1] = fmaf(lo.y, wv, acc[1]);
      acc[2] = fmaf(lo.z, wv, acc[2]); acc[3] = fmaf(lo.w, wv, acc[3]);
      acc[4] = fmaf(hi.x, wv, acc[4]); acc[5] = fmaf(hi.y, wv, acc[5]);
      acc[6] = fmaf(hi.z, wv, acc[6]); acc[7] = fmaf(hi.w, wv, acc[7]);
    }
#pragma unroll
    for (int nd = 0; nd < 8; ++nd) y[(size_t)(nbase + nd) * H + lane] = acc[nd];
  }
}

__global__ __launch_bounds__(256) void k_reduce256(const int* __restrict__ cnt, int* __restrict__ bsum) {
  __shared__ int s[256];
  int t = threadIdx.x;
  s[t] = cnt[blockIdx.x * 256 + t];
  __syncthreads();
  for (int d = 128; d > 0; d >>= 1) {
    if (t < d) s[t] += s[t + d];
    __syncthreads();
  }
  if (t == 0) bsum[blockIdx.x] = s[0];
}

__global__ __launch_bounds__(512) void k_scan512(const int* __restrict__ bsum, int* __restrict__ boff) {
  __shared__ int s[512];
  int t = threadIdx.x;
  int v = bsum[t];
  s[t] = v;
  __syncthreads();
  for (int d = 1; d < 512; d <<= 1) {
    int add = (t >= d) ? s[t - d] : 0;
    __syncthreads();
    s[t] += add;
    __syncthreads();
  }
  boff[t] = s[t] - v;  // exclusive
}

__global__ __launch_bounds__(256) void k_scanfin(const int* __restrict__ cnt, const int* __restrict__ boff,
                                                 int* __restrict__ rowptr) {
  __shared__ int s[256];
  int b = blockIdx.x, t = threadIdx.x;
  int idx = b * 256 + t;
  int v = cnt[idx];
  s[t] = v;
  __syncthreads();
  for (int d = 1; d < 256; d <<= 1) {
    int add = (t >= d) ? s[t - d] : 0;
    __syncthreads();
    s[t] += add;
    __syncthreads();
  }
  rowptr[idx] = boff[b] + s[t] - v;
  if (idx == N2 - 1) rowptr[N2] = boff[b] + s[t];
}

// atomic-free CSR fill: col[rowptr[dst] + rank] = src
__global__ __launch_bounds__(256) void k_fill2(const int* __restrict__ src1, const int* __restrict__ dst1,
                                               const int* __restrict__ src2, const int* __restrict__ dst2,
                                               const int* __restrict__ rank, const int* __restrict__ rowptr,
                                               int* __restrict__ col) {
  int b = blockIdx.x;
  const int* s = (b < 2048) ? src1 : src2;
  const int* d = (b < 2048) ? dst1 : dst2;
  int off = (b < 2048) ? 0 : N;
  int rbase = (b < 2048) ? 0 : E;
  for (int e = (b & 2047) * 256 + threadIdx.x; e < E; e += 2048 * 256) {
    int dd = off + d[e];
    col[rowptr[dd] + rank[rbase + e]] = off + s[e];
  }
}

// ---------------- gather: out[n] = relu(in[n] + sum_{j->n} in[j] + bias) ----------------

__global__ __launch_bounds__(256) void k_gather(const float* __restrict__ in, const int* __restrict__ rowptr,
                                                const int* __restrict__ col, const float* __restrict__ bias,
                                                float* __restrict__ out) {
  int tid = threadIdx.x, lane = tid & 63, sub = tid >> 6;
  int n = blockIdx.x * 4 + sub;
  int p0 = rowptr[n], p1 = rowptr[n + 1];
  float a = in[(size_t)n * H + lane] + bias[lane];
  int p = p0;
  for (; p + 16 <= p1; p += 16) {
    int myc = (lane < 16) ? col[p + lane] : 0;
    float v[16];
#pragma unroll
    for (int i = 0; i < 16; ++i) {
      int c = __shfl(myc, i, 64);
      v[i] = in[(size_t)c * H + lane];
    }
#pragma unroll
    for (int i = 0; i < 16; ++i) a += v[i];
  }
  if (p < p1) {
    int cnt = p1 - p;
    int myc = (lane < 16 && p + lane < p1) ? col[p + lane] : 0;
#pragma unroll
    for (int i = 0; i < 16; ++i) {
      if (i < cnt) {
        int c = __shfl(myc, i, 64);
        a += in[(size_t)c * H + lane];
      }
    }
  }
  out[(size_t)n * H + lane] = fmaxf(a, 0.f);
}

// ---------------- dense helpers ----------------

__device__ __forceinline__ void fma8(float (&acc)[8], const float* p, float wv) {
  float4 lo = *(const float4*)(p);
  float4 hi = *(const float4*)(p + 4);
  acc[0] = fmaf(lo.x, wv, acc[0]);
  acc[1] = fmaf(lo.y, wv, acc[1]);
  acc[2] = fmaf(lo.z, wv, acc[2]);
  acc[3] = fmaf(lo.w, wv, acc[3]);
  acc[4] = fmaf(hi.x, wv, acc[4]);
  acc[5] = fmaf(hi.y, wv, acc[5]);
  acc[6] = fmaf(hi.z, wv, acc[6]);
  acc[7] = fmaf(hi.w, wv, acc[7]);
}

// out = relu(in@Wa + ba) @ Wb
__global__ __launch_bounds__(256) void k_mid(const float* __restrict__ in, const float* __restrict__ Wa,
                                             const float* __restrict__ ba, const float* __restrict__ Wb,
                                             float* __restrict__ out) {
  __shared__ float sWa[H * H];
  __shared__ float sWb[H * H];
  __shared__ __align__(16) float st[4][H][8];
  int tid = threadIdx.x, lane = tid & 63, sub = tid >> 6;
  for (int i = tid; i < H * H; i += 256) sWa[i] = Wa[i];
  for (int i = tid; i < H * H; i += 256) sWb[i] = Wb[i];
  float biasA = ba[lane];
  __syncthreads();
  int nbase = blockIdx.x * 32 + sub * 8;
#pragma unroll
  for (int nd = 0; nd < 8; ++nd) st[sub][lane][nd] = in[(size_t)(nbase + nd) * H + lane];
  float acc[8];
#pragma unroll
  for (int nd = 0; nd < 8; ++nd) acc[nd] = biasA;
  for (int k = 0; k < H; ++k) fma8(acc, &st[sub][k][0], sWa[k * H + lane]);
#pragma unroll
  for (int nd = 0; nd < 8; ++nd) st[sub][lane][nd] = fmaxf(acc[nd], 0.f);
  float acc2[8];
#pragma unroll
  for (int nd = 0; nd < 8; ++nd) acc2[nd] = 0.f;
  for (int k = 0; k < H; ++k) fma8(acc2, &st[sub][k][0], sWb[k * H + lane]);
#pragma unroll
  for (int nd = 0; nd < 8; ++nd) out[(size_t)(nbase + nd) * H + lane] = acc2[nd];
}

// h = relu(in@Wa + ba); write L2-normalized h; write per-32-node-tile pool partials.
__global__ __launch_bounds__(256) void k_last(const float* __restrict__ in, const float* __restrict__ Wa,
                                              const float* __restrict__ ba, float* __restrict__ outn,
                                              float* __restrict__ pg) {
  __shared__ float sWa[H * H];
  __shared__ __align__(16) float st[4][H][8];
  __shared__ float sacc[4][64];
  int tid = threadIdx.x, lane = tid & 63, sub = tid >> 6;
  for (int i = tid; i < H * H; i += 256) sWa[i] = Wa[i];
  float biasA = ba[lane];
  __syncthreads();
  int nbase = blockIdx.x * 32 + sub * 8;
#pragma unroll
  for (int nd = 0; nd < 8; ++nd) st[sub][lane][nd] = in[(size_t)(nbase + nd) * H + lane];
  float acc[8];
#pragma unroll
  for (int nd = 0; nd < 8; ++nd) acc[nd] = biasA;
  for (int k = 0; k < H; ++k) fma8(acc, &st[sub][k][0], sWa[k * H + lane]);
  float psum = 0.f;
#pragma unroll
  for (int nd = 0; nd < 8; ++nd) {
    float h = fmaxf(acc[nd], 0.f);
    psum += h;
    float ss = h * h;
#pragma unroll
    for (int d = 1; d < 64; d <<= 1) ss += __shfl_xor(ss, d, 64);
    outn[(size_t)(nbase + nd) * H + lane] = h / fmaxf(sqrtf(ss), 1e-12f);
  }
  sacc[sub][lane] = psum;
  __syncthreads();
  if (sub == 0) pg[blockIdx.x * 64 + lane] = sacc[0][lane] + sacc[1][lane] + sacc[2][lane] + sacc[3][lane];
}

// ---------------- fused sim + hist + stats (float4 LDS, XOR swizzle) ----------------
__global__ __launch_bounds__(256, 3) void k_sim(const float* __restrict__ Hn, float* __restrict__ psum,
                                                float* __restrict__ psumsq, float* __restrict__ pmax,
                                                int* __restrict__ phist) {
  __shared__ float4 s1[64 * 16];   // 16 KB
  __shared__ float4 s2[128 * 16];  // 32 KB
  __shared__ int shist[64 * 17];   // 4.25 KB, 64 replicas stride 17
  __shared__ float sfin[4][4];
  int tid = threadIdx.x;
  int g = blockIdx.x >> 3, rt = blockIdx.x & 7;
  for (int i = tid; i < 64 * 17; i += 256) shist[i] = 0;
  const float4* b1p = (const float4*)(Hn + ((size_t)g * NPG + rt * 64) * H);
  for (int i = tid; i < 1024; i += 256) {
    int row = i >> 4, k4 = i & 15;
    s1[(row << 4) | (k4 ^ (row & 15))] = b1p[i];
  }
  int ty = tid >> 4, tx = tid & 15;
  int rep = (tid & 63) * 17;
  float lmax = -2.f, lsum = 0.f, lsumsq = 0.f;
  const float* H2 = Hn + (size_t)N * H;
  for (int ch = 0; ch < 4; ++ch) {
    __syncthreads();
    const float4* b2p = (const float4*)(H2 + ((size_t)g * NPG + ch * 128) * H);
    for (int i = tid; i < 2048; i += 256) {
      int row = i >> 4, k4 = i & 15;
      s2[(row << 4) | (k4 ^ (row & 15))] = b2p[i];
    }
    __syncthreads();
    float acc[4][8];
#pragma unroll
    for (int i = 0; i < 4; ++i)
#pragma unroll
      for (int j = 0; j < 8; ++j) acc[i][j] = 0.f;
#pragma unroll 2
    for (int k4 = 0; k4 < 16; ++k4) {
      int ka = k4 ^ ty, kb = k4 ^ tx;
      float4 av[4], bv[8];
#pragma unroll
      for (int i = 0; i < 4; ++i) av[i] = s1[((ty + 16 * i) << 4) | ka];
#pragma unroll
      for (int j = 0; j < 8; ++j) bv[j] = s2[((tx + 16 * j) << 4) | kb];
#pragma unroll
      for (int i = 0; i < 4; ++i)
#pragma unroll
        for (int j = 0; j < 8; ++j) {
          acc[i][j] = fmaf(av[i].x, bv[j].x, acc[i][j]);
          acc[i][j] = fmaf(av[i].y, bv[j].y, acc[i][j]);
          acc[i][j] = fmaf(av[i].z, bv[j].z, acc[i][j]);
          acc[i][j] = fmaf(av[i].w, bv[j].w, acc[i][j]);
        }
    }
#pragma unroll
    for (int i = 0; i < 4; ++i)
#pragma unroll
      for (int j = 0; j < 8; ++j) {
        float v = acc[i][j];
        lmax = fmaxf(lmax, v);
        lsum += v;
        lsumsq = fmaf(v, v, lsumsq);
        int bin = (int)((v + 1.f) * 8.f);
        bin = bin < 0 ? 0 : (bin > BINS - 1 ? BINS - 1 : bin);
        atomicAdd(&shist[rep + bin], 1);
      }
  }
#pragma unroll
  for (int d = 1; d < 64; d <<= 1) {
    lsum += __shfl_xor(lsum, d, 64);
    lsumsq += __shfl_xor(lsumsq, d, 64);
    lmax = fmaxf(lmax, __shfl_xor(lmax, d, 64));
  }
  int wv = tid >> 6, lane = tid & 63;
  if (lane == 0) {
    sfin[wv][0] = lsum;
    sfin[wv][1] = lsumsq;
    sfin[wv][2] = lmax;
  }
  __syncthreads();
  if (tid == 0) {
    psum[blockIdx.x] = sfin[0][0] + sfin[1][0] + sfin[2][0] + sfin[3][0];
    psumsq[blockIdx.x] = sfin[0][1] + sfin[1][1] + sfin[2][1] + sfin[3][1];
    pmax[blockIdx.x] = fmaxf(fmaxf(sfin[0][2], sfin[1][2]), fmaxf(sfin[2][2], sfin[3][2]));
  }
  if (tid < BINS) {
    int tot = 0;
    for (int r = 0; r < 64; ++r) tot += shist[r * 17 + tid];
    phist[blockIdx.x * BINS + tid] = tot;
  }
}

// ---------------- final feature assembly + MLP ----------------
__global__ __launch_bounds__(64) void k_final(const float* __restrict__ pg1, const float* __restrict__ pg2,
                                              const float* __restrict__ psum, const float* __restrict__ psumsq,
                                              const float* __restrict__ pmax, const int* __restrict__ phist,
                                              const float* __restrict__ w1, const float* __restrict__ b1,
                                              const float* __restrict__ w2, const float* __restrict__ b2,
                                              const float* __restrict__ w3, const float* __restrict__ b3,
                                              float* __restrict__ out) {
  __shared__ float f[FIN + 1];
  __shared__ float t1[64];
  __shared__ float t2[32];
  int g = blockIdx.x, t = threadIdx.x;
  {
    float s1v = 0.f, s2v = 0.f;
#pragma unroll
    for (int r = 0; r < 16; ++r) {
      s1v += pg1[(g * 16 + r) * 64 + t];
      s2v += pg2[(g * 16 + r) * 64 + t];
    }
    f[t]      = s1v * (1.f / NPG);
    f[64 + t] = s2v * (1.f / NPG);
  }
  if (t < BINS) {
    int tot = 0;
#pragma unroll
    for (int r = 0; r < 8; ++r) tot += phist[(g * 8 + r) * BINS + t];
    f[2 * H + t] = (float)tot * (1.f / 262144.f);
  }
  if (t == 0) {
    float s = 0.f, ss = 0.f, mx = -2.f;
#pragma unroll
    for (int r = 0; r < 8; ++r) {
      s += psum[g * 8 + r];
      ss += psumsq[g * 8 + r];
      mx = fmaxf(mx, pmax[g * 8 + r]);
    }
    const float inv = 1.f / 262144.f;
    float mean = s * inv;
    float var = fmaxf(ss * inv - mean * mean, 0.f);
    f[144] = mean;
    f[145] = mx;
    f[146] = sqrtf(var);
  }
  __syncthreads();
  float acc = b1[t];
  for (int k = 0; k < FIN; ++k) acc = fmaf(f[k], w1[k * 64 + t], acc);
  t1[t] = fmaxf(acc, 0.f);
  __syncthreads();
  if (t < 32) {
    float a2 = b2[t];
#pragma unroll 8
    for (int k = 0; k < 64; ++k) a2 = fmaf(t1[k], w2[k * 32 + t], a2);
    t2[t] = fmaxf(a2, 0.f);
  }
  __syncthreads();
  if (t == 0) {
    float a3 = b3[0];
#pragma unroll
    for (int k = 0; k < 32; ++k) a3 = fmaf(t2[k], w3[k], a3);
    out[g] = a3;
  }
}

}  // namespace

extern "C" void kernel_launch(void* const* d_in, const int* in_sizes, int n_in, void* d_out, int out_size,
                              void* d_ws, size_t ws_size, hipStream_t stream) {
  const float* x1 = (const float*)d_in[0];
  const int* e1 = (const int*)d_in[1];
  const float* x2 = (const float*)d_in[3];
  const int* e2 = (const int*)d_in[4];
  const float* enc_w1 = (const float*)d_in[6];
  const float* enc_b1 = (const float*)d_in[7];
  const float* enc_w2 = (const float*)d_in[8];
  const float* enc_b2 = (const float*)d_in[9];
  const float* enc_w3 = (const float*)d_in[10];
  const float* enc_b3 = (const float*)d_in[11];
  const float* enc_w4 = (const float*)d_in[12];
  const float* enc_b4 = (const float*)d_in[13];
  const float* mw1 = (const float*)d_in[14];
  const float* mb1 = (const float*)d_in[15];
  const float* mw2 = (const float*)d_in[16];
  const float* mb2 = (const float*)d_in[17];
  const float* mw3 = (const float*)d_in[18];
  const float* mb3 = (const float*)d_in[19];
  float* out = (float*)d_out;

  char* wsc = (char*)d_ws;
  size_t off = 0;
  auto alloc = [&](size_t bytes) -> void* {
    void* p = wsc + off;
    off += (bytes + 255) & ~(size_t)255;
    return p;
  };
  float* bufA = (float*)alloc((size_t)N2 * H * 4);  // 32 MB (also final Hn)
  float* bufB = (float*)alloc((size_t)N2 * H * 4);  // 32 MB (aliased as rank[] during CSR build)
  int* rowptr = (int*)alloc((size_t)(N2 + 1) * 4);
  int* colidx = (int*)alloc((size_t)2 * E * 4);     // 8 MB
  int* cnt = (int*)alloc((size_t)N2 * 4);
  int* bsum = (int*)alloc(512 * 4);
  int* boff = (int*)alloc(512 * 4);
  float* pg = (float*)alloc((size_t)(N2 / 32) * 64 * 4);  // 1 MB
  float* psum = (float*)alloc(1024 * 4);
  float* psumsq = (float*)alloc(1024 * 4);
  float* pmaxa = (float*)alloc(1024 * 4);
  int* phist = (int*)alloc((size_t)1024 * BINS * 4);
  (void)ws_size;
  (void)in_sizes;
  (void)n_in;
  (void)out_size;

  const int* src1 = e1;
  const int* dst1 = e1 + E;
  const int* src2 = e2;
  const int* dst2 = e2 + E;
  int* rank = (int*)bufB;  // dead until gather1 overwrites bufB (fill2 consumed it by then)

  // CSR count+rank fused with xw (independent work overlap)
  hipMemsetAsync(cnt, 0, (size_t)N2 * 4, stream);
  k_count_xw<<<8192, 256, 0, stream>>>(dst1, dst2, cnt, rank, x1, x2, enc_w1, bufA);
  k_reduce256<<<512, 256, 0, stream>>>(cnt, bsum);
  k_scan512<<<1, 512, 0, stream>>>(bsum, boff);
  k_scanfin<<<512, 256, 0, stream>>>(cnt, boff, rowptr);
  k_fill2<<<4096, 256, 0, stream>>>(src1, dst1, src2, dst2, rank, rowptr, colidx);

  // encoder over 2N nodes: A -> B -> A -> B -> A(normalized)
  k_gather<<<N2 / 4, 256, 0, stream>>>(bufA, rowptr, colidx, enc_b1, bufB);
  k_mid<<<N2 / 32, 256, 0, stream>>>(bufB, enc_w2, enc_b2, enc_w3, bufA);
  k_gather<<<N2 / 4, 256, 0, stream>>>(bufA, rowptr, colidx, enc_b3, bufB);
  k_last<<<N2 / 32, 256, 0, stream>>>(bufB, enc_w4, enc_b4, bufA, pg);

  k_sim<<<B * 8, 256, 0, stream>>>(bufA, psum, psumsq, pmaxa, phist);
  k_final<<<B, 64, 0, stream>>>(pg, pg + (size_t)2048 * 64, psum, psumsq, pmaxa, phist, mw1, mb1, mw2, mb2,
                                mw3, mb3, out);
}

// Round 5
// 441.483 us; speedup vs baseline: 2.5275x; 1.1946x over previous
//
#include <hip/hip_runtime.h>
#include <hip/hip_bf16.h>

namespace {

constexpr int N    = 65536;
constexpr int E    = 1048576;
constexpr int N2   = 2 * N;      // both sides concatenated
constexpr int B    = 128;
constexpr int NPG  = 512;
constexpr int IN   = 128;
constexpr int H    = 64;
constexpr int BINS = 16;
constexpr int FIN  = 2 * H + BINS + 3;  // 147
// CSR bucket scheme: 512 buckets of 256 dsts; 512 slices of 4096 edges.
constexpr int NBUCKET = 512;
constexpr int NSLICE  = 512;
constexpr int SLICE_E = 4096;

// ---------------- P1 (blocks 0..511): bucket histogram per slice, LDS only.
// ---------------- blocks 512..4607: y = x @ W1 (independent work, co-scheduled).

__global__ __launch_bounds__(256) void k_p1_xw(const int* __restrict__ dst1, const int* __restrict__ dst2,
                                               int* __restrict__ bcnt,
                                               const float* __restrict__ x1, const float* __restrict__ x2,
                                               const float* __restrict__ W, float* __restrict__ y) {
  __shared__ float sW[IN * H];                     // 32 KB
  __shared__ __align__(16) float sx[4][IN][8];     // 16 KB
  __shared__ int hist[NBUCKET];                    // 2 KB
  int b = blockIdx.x, tid = threadIdx.x;
  if (b < NSLICE) {
    hist[tid] = 0;
    hist[tid + 256] = 0;
    __syncthreads();
    const int* d = (b < 256) ? dst1 : dst2;
    int ebase = (b & 255) * SLICE_E;
    int boff = (b < 256) ? 0 : 256;  // side2 dst+N -> bucket+256 (N = 256*256)
    for (int i = tid; i < SLICE_E; i += 256) atomicAdd(&hist[boff + (d[ebase + i] >> 8)], 1);
    __syncthreads();
    for (int k = tid; k < NBUCKET; k += 256) bcnt[b * NBUCKET + k] = hist[k];
  } else {
    int bx = b - NSLICE;
    int lane = tid & 63, sub = tid >> 6;
    for (int i = tid; i < IN * H; i += 256) sW[i] = W[i];
    __syncthreads();
    int nbase = bx * 32 + sub * 8;
    const float* xp = (nbase < N) ? (x1 + (size_t)nbase * IN) : (x2 + (size_t)(nbase - N) * IN);
#pragma unroll
    for (int nd = 0; nd < 8; ++nd) {
      const float* xr = xp + (size_t)nd * IN;
      sx[sub][lane][nd]      = xr[lane];
      sx[sub][lane + 64][nd] = xr[lane + 64];
    }
    // same-wave LDS producer/consumer: no barrier needed
    float acc[8];
#pragma unroll
    for (int nd = 0; nd < 8; ++nd) acc[nd] = 0.f;
    for (int k = 0; k < IN; ++k) {
      float wv = sW[k * H + lane];
      const float* p = &sx[sub][k][0];
      float4 lo = *(const float4*)(p);
      float4 hi = *(const float4*)(p + 4);
      acc[0] = fmaf(lo.x, wv, acc[0]); acc[1] = fmaf(lo.y, wv, acc[1]);
      acc[2] = fmaf(lo.z, wv, acc[2]); acc[3] = fmaf(lo.w, wv, acc[3]);
      acc[4] = fmaf(hi.x, wv, acc[4]); acc[5] = fmaf(hi.y, wv, acc[5]);
      acc[6] = fmaf(hi.z, wv, acc[6]); acc[7] = fmaf(hi.w, wv, acc[7]);
    }
#pragma unroll
    for (int nd = 0; nd < 8; ++nd) y[(size_t)(nbase + nd) * H + lane] = acc[nd];
  }
}

// P2: per-bucket exclusive scan across slices. boffs[bucket][slice]; tot[bucket].
__global__ __launch_bounds__(256) void k_scanrows(const int* __restrict__ bcnt, int* __restrict__ boffs,
                                                  int* __restrict__ tot) {
  __shared__ int s[NSLICE];
  int b = blockIdx.x, t = threadIdx.x;
  int v0 = bcnt[t * NBUCKET + b], v1 = bcnt[(t + 256) * NBUCKET + b];
  s[t] = v0;
  s[t + 256] = v1;
  __syncthreads();
  for (int d = 1; d < NSLICE; d <<= 1) {
    int a0 = (t >= d) ? s[t - d] : 0;
    int a1 = (t + 256 >= d) ? s[t + 256 - d] : 0;
    __syncthreads();
    s[t] += a0;
    s[t + 256] += a1;
    __syncthreads();
  }
  boffs[b * NSLICE + t] = s[t] - v0;
  boffs[b * NSLICE + t + 256] = s[t + 256] - v1;
  if (t == 255) tot[b] = s[NSLICE - 1];
}

// P3: exclusive scan of bucket totals -> bucketBase[0..512].
__global__ __launch_bounds__(512) void k_scantot(const int* __restrict__ tot, int* __restrict__ bucketBase) {
  __shared__ int s[NBUCKET];
  int t = threadIdx.x;
  int v = tot[t];
  s[t] = v;
  __syncthreads();
  for (int d = 1; d < NBUCKET; d <<= 1) {
    int a = (t >= d) ? s[t - d] : 0;
    __syncthreads();
    s[t] += a;
    __syncthreads();
  }
  bucketBase[t] = s[t] - v;
  if (t == NBUCKET - 1) bucketBase[NBUCKET] = s[t];
}

// P5: scatter edges into bucket-grouped ebuf, packed (dstLow8 << 17) | src. LDS cursors only.
__global__ __launch_bounds__(256) void k_p5(const int* __restrict__ src1, const int* __restrict__ dst1,
                                            const int* __restrict__ src2, const int* __restrict__ dst2,
                                            const int* __restrict__ boffs, const int* __restrict__ bucketBase,
                                            int* __restrict__ ebuf) {
  __shared__ int sofs[NBUCKET];
  __shared__ int cur[NBUCKET];
  int b = blockIdx.x, tid = threadIdx.x;
  for (int k = tid; k < NBUCKET; k += 256) {
    sofs[k] = bucketBase[k] + boffs[k * NSLICE + b];
    cur[k] = 0;
  }
  __syncthreads();
  const int* sr = (b < 256) ? src1 : src2;
  const int* d  = (b < 256) ? dst1 : dst2;
  int ebase = (b & 255) * SLICE_E;
  int off = (b < 256) ? 0 : N;
  int boff2 = (b < 256) ? 0 : 256;
  for (int i = tid; i < SLICE_E; i += 256) {
    int dd = d[ebase + i];
    int sv = off + sr[ebase + i];
    int bucket = boff2 + (dd >> 8);
    int r = atomicAdd(&cur[bucket], 1);
    ebuf[sofs[bucket] + r] = ((dd & 255) << 17) | sv;
  }
}

// P6: per-bucket CSR finalize (contiguous edge segment). LDS count+scan+scatter.
__global__ __launch_bounds__(256) void k_p6(const int* __restrict__ ebuf, const int* __restrict__ bucketBase,
                                            int* __restrict__ rowptr, int* __restrict__ col) {
  __shared__ int c256[256];
  __shared__ int lofs[256];
  int b = blockIdx.x, t = threadIdx.x;
  int e0 = bucketBase[b], e1 = bucketBase[b + 1];
  c256[t] = 0;
  __syncthreads();
  for (int i = e0 + t; i < e1; i += 256) atomicAdd(&c256[(ebuf[i] >> 17) & 255], 1);
  __syncthreads();
  int v = c256[t];
  lofs[t] = v;
  __syncthreads();
  for (int d = 1; d < 256; d <<= 1) {
    int a = (t >= d) ? lofs[t - d] : 0;
    __syncthreads();
    lofs[t] += a;
    __syncthreads();
  }
  int excl = lofs[t] - v;
  rowptr[b * 256 + t] = e0 + excl;
  if (b == NBUCKET - 1 && t == 255) rowptr[N2] = e1;
  c256[t] = 0;
  lofs[t] = excl;
  __syncthreads();
  for (int i = e0 + t; i < e1; i += 256) {
    int pk = ebuf[i];
    int dl = (pk >> 17) & 255;
    int r = atomicAdd(&c256[dl], 1);
    col[e0 + lofs[dl] + r] = pk & 0x1FFFF;
  }
}

// ---------------- gather: out[n] = relu(in[n] + sum_{j->n} in[j] + bias) ----------------

__global__ __launch_bounds__(256) void k_gather(const float* __restrict__ in, const int* __restrict__ rowptr,
                                                const int* __restrict__ col, const float* __restrict__ bias,
                                                float* __restrict__ out) {
  int tid = threadIdx.x, lane = tid & 63, sub = tid >> 6;
  int n = blockIdx.x * 4 + sub;
  int p0 = rowptr[n], p1 = rowptr[n + 1];
  float a = in[(size_t)n * H + lane] + bias[lane];
  int p = p0;
  for (; p + 16 <= p1; p += 16) {
    int myc = (lane < 16) ? col[p + lane] : 0;
    float v[16];
#pragma unroll
    for (int i = 0; i < 16; ++i) {
      int c = __shfl(myc, i, 64);
      v[i] = in[(size_t)c * H + lane];
    }
#pragma unroll
    for (int i = 0; i < 16; ++i) a += v[i];
  }
  if (p < p1) {
    int cnt = p1 - p;
    int myc = (lane < 16 && p + lane < p1) ? col[p + lane] : 0;
#pragma unroll
    for (int i = 0; i < 16; ++i) {
      if (i < cnt) {
        int c = __shfl(myc, i, 64);
        a += in[(size_t)c * H + lane];
      }
    }
  }
  out[(size_t)n * H + lane] = fmaxf(a, 0.f);
}

// ---------------- dense helpers ----------------

__device__ __forceinline__ void fma8(float (&acc)[8], const float* p, float wv) {
  float4 lo = *(const float4*)(p);
  float4 hi = *(const float4*)(p + 4);
  acc[0] = fmaf(lo.x, wv, acc[0]);
  acc[1] = fmaf(lo.y, wv, acc[1]);
  acc[2] = fmaf(lo.z, wv, acc[2]);
  acc[3] = fmaf(lo.w, wv, acc[3]);
  acc[4] = fmaf(hi.x, wv, acc[4]);
  acc[5] = fmaf(hi.y, wv, acc[5]);
  acc[6] = fmaf(hi.z, wv, acc[6]);
  acc[7] = fmaf(hi.w, wv, acc[7]);
}

// out = relu(in@Wa + ba) @ Wb
__global__ __launch_bounds__(256) void k_mid(const float* __restrict__ in, const float* __restrict__ Wa,
                                             const float* __restrict__ ba, const float* __restrict__ Wb,
                                             float* __restrict__ out) {
  __shared__ float sWa[H * H];
  __shared__ float sWb[H * H];
  __shared__ __align__(16) float st[4][H][8];
  int tid = threadIdx.x, lane = tid & 63, sub = tid >> 6;
  for (int i = tid; i < H * H; i += 256) sWa[i] = Wa[i];
  for (int i = tid; i < H * H; i += 256) sWb[i] = Wb[i];
  float biasA = ba[lane];
  __syncthreads();
  int nbase = blockIdx.x * 32 + sub * 8;
#pragma unroll
  for (int nd = 0; nd < 8; ++nd) st[sub][lane][nd] = in[(size_t)(nbase + nd) * H + lane];
  float acc[8];
#pragma unroll
  for (int nd = 0; nd < 8; ++nd) acc[nd] = biasA;
  for (int k = 0; k < H; ++k) fma8(acc, &st[sub][k][0], sWa[k * H + lane]);
#pragma unroll
  for (int nd = 0; nd < 8; ++nd) st[sub][lane][nd] = fmaxf(acc[nd], 0.f);
  float acc2[8];
#pragma unroll
  for (int nd = 0; nd < 8; ++nd) acc2[nd] = 0.f;
  for (int k = 0; k < H; ++k) fma8(acc2, &st[sub][k][0], sWb[k * H + lane]);
#pragma unroll
  for (int nd = 0; nd < 8; ++nd) out[(size_t)(nbase + nd) * H + lane] = acc2[nd];
}

// h = relu(in@Wa + ba); write L2-normalized h; write per-32-node-tile pool partials.
__global__ __launch_bounds__(256) void k_last(const float* __restrict__ in, const float* __restrict__ Wa,
                                              const float* __restrict__ ba, float* __restrict__ outn,
                                              float* __restrict__ pg) {
  __shared__ float sWa[H * H];
  __shared__ __align__(16) float st[4][H][8];
  __shared__ float sacc[4][64];
  int tid = threadIdx.x, lane = tid & 63, sub = tid >> 6;
  for (int i = tid; i < H * H; i += 256) sWa[i] = Wa[i];
  float biasA = ba[lane];
  __syncthreads();
  int nbase = blockIdx.x * 32 + sub * 8;
#pragma unroll
  for (int nd = 0; nd < 8; ++nd) st[sub][lane][nd] = in[(size_t)(nbase + nd) * H + lane];
  float acc[8];
#pragma unroll
  for (int nd = 0; nd < 8; ++nd) acc[nd] = biasA;
  for (int k = 0; k < H; ++k) fma8(acc, &st[sub][k][0], sWa[k * H + lane]);
  float psum = 0.f;
#pragma unroll
  for (int nd = 0; nd < 8; ++nd) {
    float h = fmaxf(acc[nd], 0.f);
    psum += h;
    float ss = h * h;
#pragma unroll
    for (int d = 1; d < 64; d <<= 1) ss += __shfl_xor(ss, d, 64);
    outn[(size_t)(nbase + nd) * H + lane] = h / fmaxf(sqrtf(ss), 1e-12f);
  }
  sacc[sub][lane] = psum;
  __syncthreads();
  if (sub == 0) pg[blockIdx.x * 64 + lane] = sacc[0][lane] + sacc[1][lane] + sacc[2][lane] + sacc[3][lane];
}

// ---------------- fused sim + hist + stats (float4 LDS, XOR swizzle) ----------------
__global__ __launch_bounds__(256, 3) void k_sim(const float* __restrict__ Hn, float* __restrict__ psum,
                                                float* __restrict__ psumsq, float* __restrict__ pmax,
                                                int* __restrict__ phist) {
  __shared__ float4 s1[64 * 16];   // 16 KB
  __shared__ float4 s2[128 * 16];  // 32 KB
  __shared__ int shist[64 * 17];   // 4.25 KB, 64 replicas stride 17
  __shared__ float sfin[4][4];
  int tid = threadIdx.x;
  int g = blockIdx.x >> 3, rt = blockIdx.x & 7;
  for (int i = tid; i < 64 * 17; i += 256) shist[i] = 0;
  const float4* b1p = (const float4*)(Hn + ((size_t)g * NPG + rt * 64) * H);
  for (int i = tid; i < 1024; i += 256) {
    int row = i >> 4, k4 = i & 15;
    s1[(row << 4) | (k4 ^ (row & 15))] = b1p[i];
  }
  int ty = tid >> 4, tx = tid & 15;
  int rep = (tid & 63) * 17;
  float lmax = -2.f, lsum = 0.f, lsumsq = 0.f;
  const float* H2 = Hn + (size_t)N * H;
  for (int ch = 0; ch < 4; ++ch) {
    __syncthreads();
    const float4* b2p = (const float4*)(H2 + ((size_t)g * NPG + ch * 128) * H);
    for (int i = tid; i < 2048; i += 256) {
      int row = i >> 4, k4 = i & 15;
      s2[(row << 4) | (k4 ^ (row & 15))] = b2p[i];
    }
    __syncthreads();
    float acc[4][8];
#pragma unroll
    for (int i = 0; i < 4; ++i)
#pragma unroll
      for (int j = 0; j < 8; ++j) acc[i][j] = 0.f;
#pragma unroll 2
    for (int k4 = 0; k4 < 16; ++k4) {
      int ka = k4 ^ ty, kb = k4 ^ tx;
      float4 av[4], bv[8];
#pragma unroll
      for (int i = 0; i < 4; ++i) av[i] = s1[((ty + 16 * i) << 4) | ka];
#pragma unroll
      for (int j = 0; j < 8; ++j) bv[j] = s2[((tx + 16 * j) << 4) | kb];
#pragma unroll
      for (int i = 0; i < 4; ++i)
#pragma unroll
        for (int j = 0; j < 8; ++j) {
          acc[i][j] = fmaf(av[i].x, bv[j].x, acc[i][j]);
          acc[i][j] = fmaf(av[i].y, bv[j].y, acc[i][j]);
          acc[i][j] = fmaf(av[i].z, bv[j].z, acc[i][j]);
          acc[i][j] = fmaf(av[i].w, bv[j].w, acc[i][j]);
        }
    }
#pragma unroll
    for (int i = 0; i < 4; ++i)
#pragma unroll
      for (int j = 0; j < 8; ++j) {
        float v = acc[i][j];
        lmax = fmaxf(lmax, v);
        lsum += v;
        lsumsq = fmaf(v, v, lsumsq);
        int bin = (int)((v + 1.f) * 8.f);
        bin = bin < 0 ? 0 : (bin > BINS - 1 ? BINS - 1 : bin);
        atomicAdd(&shist[rep + bin], 1);
      }
  }
#pragma unroll
  for (int d = 1; d < 64; d <<= 1) {
    lsum += __shfl_xor(lsum, d, 64);
    lsumsq += __shfl_xor(lsumsq, d, 64);
    lmax = fmaxf(lmax, __shfl_xor(lmax, d, 64));
  }
  int wv = tid >> 6, lane = tid & 63;
  if (lane == 0) {
    sfin[wv][0] = lsum;
    sfin[wv][1] = lsumsq;
    sfin[wv][2] = lmax;
  }
  __syncthreads();
  if (tid == 0) {
    psum[blockIdx.x] = sfin[0][0] + sfin[1][0] + sfin[2][0] + sfin[3][0];
    psumsq[blockIdx.x] = sfin[0][1] + sfin[1][1] + sfin[2][1] + sfin[3][1];
    pmax[blockIdx.x] = fmaxf(fmaxf(sfin[0][2], sfin[1][2]), fmaxf(sfin[2][2], sfin[3][2]));
  }
  if (tid < BINS) {
    int tot = 0;
    for (int r = 0; r < 64; ++r) tot += shist[r * 17 + tid];
    phist[blockIdx.x * BINS + tid] = tot;
  }
}

// ---------------- final feature assembly + MLP ----------------
__global__ __launch_bounds__(64) void k_final(const float* __restrict__ pg1, const float* __restrict__ pg2,
                                              const float* __restrict__ psum, const float* __restrict__ psumsq,
                                              const float* __restrict__ pmax, const int* __restrict__ phist,
                                              const float* __restrict__ w1, const float* __restrict__ b1,
                                              const float* __restrict__ w2, const float* __restrict__ b2,
                                              const float* __restrict__ w3, const float* __restrict__ b3,
                                              float* __restrict__ out) {
  __shared__ float f[FIN + 1];
  __shared__ float t1[64];
  __shared__ float t2[32];
  int g = blockIdx.x, t = threadIdx.x;
  {
    float s1v = 0.f, s2v = 0.f;
#pragma unroll
    for (int r = 0; r < 16; ++r) {
      s1v += pg1[(g * 16 + r) * 64 + t];
      s2v += pg2[(g * 16 + r) * 64 + t];
    }
    f[t]      = s1v * (1.f / NPG);
    f[64 + t] = s2v * (1.f / NPG);
  }
  if (t < BINS) {
    int tot = 0;
#pragma unroll
    for (int r = 0; r < 8; ++r) tot += phist[(g * 8 + r) * BINS + t];
    f[2 * H + t] = (float)tot * (1.f / 262144.f);
  }
  if (t == 0) {
    float s = 0.f, ss = 0.f, mx = -2.f;
#pragma unroll
    for (int r = 0; r < 8; ++r) {
      s += psum[g * 8 + r];
      ss += psumsq[g * 8 + r];
      mx = fmaxf(mx, pmax[g * 8 + r]);
    }
    const float inv = 1.f / 262144.f;
    float mean = s * inv;
    float var = fmaxf(ss * inv - mean * mean, 0.f);
    f[144] = mean;
    f[145] = mx;
    f[146] = sqrtf(var);
  }
  __syncthreads();
  float acc = b1[t];
  for (int k = 0; k < FIN; ++k) acc = fmaf(f[k], w1[k * 64 + t], acc);
  t1[t] = fmaxf(acc, 0.f);
  __syncthreads();
  if (t < 32) {
    float a2 = b2[t];
#pragma unroll 8
    for (int k = 0; k < 64; ++k) a2 = fmaf(t1[k], w2[k * 32 + t], a2);
    t2[t] = fmaxf(a2, 0.f);
  }
  __syncthreads();
  if (t == 0) {
    float a3 = b3[0];
#pragma unroll
    for (int k = 0; k < 32; ++k) a3 = fmaf(t2[k], w3[k], a3);
    out[g] = a3;
  }
}

}  // namespace

extern "C" void kernel_launch(void* const* d_in, const int* in_sizes, int n_in, void* d_out, int out_size,
                              void* d_ws, size_t ws_size, hipStream_t stream) {
  const float* x1 = (const float*)d_in[0];
  const int* e1 = (const int*)d_in[1];
  const float* x2 = (const float*)d_in[3];
  const int* e2 = (const int*)d_in[4];
  const float* enc_w1 = (const float*)d_in[6];
  const float* enc_b1 = (const float*)d_in[7];
  const float* enc_w2 = (const float*)d_in[8];
  const float* enc_b2 = (const float*)d_in[9];
  const float* enc_w3 = (const float*)d_in[10];
  const float* enc_b3 = (const float*)d_in[11];
  const float* enc_w4 = (const float*)d_in[12];
  const float* enc_b4 = (const float*)d_in[13];
  const float* mw1 = (const float*)d_in[14];
  const float* mb1 = (const float*)d_in[15];
  const float* mw2 = (const float*)d_in[16];
  const float* mb2 = (const float*)d_in[17];
  const float* mw3 = (const float*)d_in[18];
  const float* mb3 = (const float*)d_in[19];
  float* out = (float*)d_out;

  char* wsc = (char*)d_ws;
  size_t off = 0;
  auto alloc = [&](size_t bytes) -> void* {
    void* p = wsc + off;
    off += (bytes + 255) & ~(size_t)255;
    return p;
  };
  float* bufA = (float*)alloc((size_t)N2 * H * 4);  // 32 MB (also final Hn)
  float* bufB = (float*)alloc((size_t)N2 * H * 4);  // 32 MB (aliased as ebuf during CSR build)
  int* rowptr = (int*)alloc((size_t)(N2 + 1) * 4);
  int* colidx = (int*)alloc((size_t)2 * E * 4);     // 8 MB
  int* bcnt = (int*)alloc((size_t)NSLICE * NBUCKET * 4);   // 1 MB
  int* boffs = (int*)alloc((size_t)NBUCKET * NSLICE * 4);  // 1 MB
  int* tot = (int*)alloc((size_t)NBUCKET * 4);
  int* bucketBase = (int*)alloc((size_t)(NBUCKET + 1) * 4);
  float* pg = (float*)alloc((size_t)(N2 / 32) * 64 * 4);   // 1 MB
  float* psum = (float*)alloc(1024 * 4);
  float* psumsq = (float*)alloc(1024 * 4);
  float* pmaxa = (float*)alloc(1024 * 4);
  int* phist = (int*)alloc((size_t)1024 * BINS * 4);
  (void)ws_size;
  (void)in_sizes;
  (void)n_in;
  (void)out_size;

  const int* src1 = e1;
  const int* dst1 = e1 + E;
  const int* src2 = e2;
  const int* dst2 = e2 + E;
  int* ebuf = (int*)bufB;  // dead once k_p6 consumed it (before gather1 writes bufB)

  // CSR build (LDS-atomic bucket scheme) + xw co-scheduled
  k_p1_xw<<<NSLICE + N2 / 32, 256, 0, stream>>>(dst1, dst2, bcnt, x1, x2, enc_w1, bufA);
  k_scanrows<<<NBUCKET, 256, 0, stream>>>(bcnt, boffs, tot);
  k_scantot<<<1, 512, 0, stream>>>(tot, bucketBase);
  k_p5<<<NSLICE, 256, 0, stream>>>(src1, dst1, src2, dst2, boffs, bucketBase, ebuf);
  k_p6<<<NBUCKET, 256, 0, stream>>>(ebuf, bucketBase, rowptr, colidx);

  // encoder over 2N nodes: A -> B -> A -> B -> A(normalized)
  k_gather<<<N2 / 4, 256, 0, stream>>>(bufA, rowptr, colidx, enc_b1, bufB);
  k_mid<<<N2 / 32, 256, 0, stream>>>(bufB, enc_w2, enc_b2, enc_w3, bufA);
  k_gather<<<N2 / 4, 256, 0, stream>>>(bufA, rowptr, colidx, enc_b3, bufB);
  k_last<<<N2 / 32, 256, 0, stream>>>(bufB, enc_w4, enc_b4, bufA, pg);

  k_sim<<<B * 8, 256, 0, stream>>>(bufA, psum, psumsq, pmaxa, phist);
  k_final<<<B, 64, 0, stream>>>(pg, pg + (size_t)2048 * 64, psum, psumsq, pmaxa, phist, mw1, mb1, mw2, mb2,
                                mw3, mb3, out);
}